// Round 2
// baseline (10731.660 us; speedup 1.0000x reference)
//
#include <hip/hip_runtime.h>
#include <stdint.h>

#define TT 2048
#define DD 256
#define GG 1024
#define NWG 32
#define HC 8
#define HWORDS 8192   // 32 rows x 256 cols, one tagged word per h value
#define RING 4

typedef __attribute__((ext_vector_type(4))) float f32x4;
typedef __attribute__((ext_vector_type(8))) short s16x8;

static __device__ __forceinline__ unsigned f2bf(float f) {
    union { float f; unsigned u; } v; v.f = f;
    return (v.u + 0x7fffu + ((v.u >> 16) & 1u)) >> 16;
}
static __device__ __forceinline__ float bf2f(unsigned b) {
    union { unsigned u; float f; } v; v.u = b << 16;
    return v.f;
}
static __device__ __forceinline__ float sigm(float x) {
    return 1.0f / (1.0f + __expf(-x));
}
static __device__ __forceinline__ float tanh_f(float x) {
    x = fminf(15.0f, fmaxf(-15.0f, x));
    float e = __expf(2.0f * x);
    return (e - 1.0f) / (e + 1.0f);
}

// Zero slot 0 of h0 (tag 0 == "h after 0 steps = 0") and ring slot 0 of h1.
// Runs every launch: graph-replay safe (all other slots are tag-checked).
__global__ void k_init(unsigned* __restrict__ h0, unsigned* __restrict__ h1) {
    int i = blockIdx.x * 256 + threadIdx.x;   // grid covers HWORDS exactly
    h0[i] = 0u;
    h1[i] = 0u;
}

// 64 WGs: wg 0..31 = layer 0 (h-cols [8w,8w+8)), wg 32..63 = layer 1.
// h exchange: tagged words (bf16(h)<<16 | step) at agent scope — the poll IS the load.
__launch_bounds__(256)
__global__ void k_scan(const float* __restrict__ x,
                       const float* __restrict__ Wi0, const float* __restrict__ Wh0,
                       const float* __restrict__ b0,
                       const float* __restrict__ Wi1, const float* __restrict__ Wh1,
                       const float* __restrict__ b1,
                       unsigned* h0w, unsigned* h1w)
{
    const int tid = threadIdx.x;
    const int wgid = blockIdx.x;
    const bool L0 = (wgid < NWG);
    const int w = L0 ? wgid : (wgid - NWG);

    const float* Wi = L0 ? Wi0 : Wi1;
    const float* Wh = L0 ? Wh0 : Wh1;
    const float* bias = L0 ? b0 : b1;

    __shared__ __align__(16) unsigned char Ap[32 * 1024];   // [32 rows][512 k] bf16, XOR-swizzled (16B granule)
    __shared__ float zbuf[4 * 32 * 9];                      // [gate][row][col pad 9]

    const int lane = tid & 63;
    const int wid = tid >> 6;      // 4 waves
    const int mt = wid & 1;        // M-tile (batch 16)
    const int nt = wid >> 1;       // N-tile (16 gate cols)

    // ---- one-time: weights into registers as MFMA B-fragments ----
    s16x8 Bfrag[16];
    {
        const int jloc = lane & 15;
        const int lcol = nt * 16 + jloc;          // local col: [i0-7 f0-7 | g0-7 o0-7]
        const int gate = lcol >> 3;
        const int jj = lcol & 7;
        const int gcol = gate * 256 + w * HC + jj;
        const int krow = (lane >> 4) * 8;
#pragma unroll
        for (int kf = 0; kf < 16; ++kf) {
            s16x8 bfv;
#pragma unroll
            for (int j = 0; j < 8; ++j) {
                int k = kf * 32 + krow + j;
                float wv = (k < 256) ? Wi[(size_t)k * GG + gcol]
                                     : Wh[(size_t)(k - 256) * GG + gcol];
                bfv[j] = (short)f2bf(wv);
            }
            Bfrag[kf] = bfv;
        }
    }

    // gate-update role: thread -> (batch gm, h-col gj)
    const int gm = tid >> 3;
    const int gj = tid & 7;
    const float bi_ = bias[0 * 256 + w * HC + gj];
    const float bf_ = bias[1 * 256 + w * HC + gj];
    const float bg_ = bias[2 * 256 + w * HC + gj];
    const float bo_ = bias[3 * 256 + w * HC + gj];

    // staging role: thread -> column-chunk cb (4 cols), row-quarter rq (rows i*4+rq)
    const int cb = tid & 63;
    const int rq = tid >> 6;

    float c_state = 0.0f;
    long long budget = 2000000LL;   // anti-hang bound; untouched in normal runs

    // Poll+stage one 256-col half of the A panel from a tagged h slot.
    // Per load instruction i the wave's lanes cover a contiguous 1KB (coalesced).
    auto poll_stage = [&](const unsigned* slotbase, unsigned tag, unsigned halfB) {
        unsigned v[8][4];
#pragma unroll
        for (int i = 0; i < 8; ++i) {
            const unsigned* p = slotbase + (((unsigned)(i * 256 + tid)) << 2);
#pragma unroll
            for (int q = 0; q < 4; ++q)
                v[i][q] = __hip_atomic_load(p + q, __ATOMIC_RELAXED, __HIP_MEMORY_SCOPE_AGENT);
        }
        for (;;) {
            bool ok = true;
#pragma unroll
            for (int i = 0; i < 8; ++i) {
                const unsigned* p = slotbase + (((unsigned)(i * 256 + tid)) << 2);
#pragma unroll
                for (int q = 0; q < 4; ++q)
                    if ((v[i][q] & 0xffffu) != tag) {
                        ok = false;
                        v[i][q] = __hip_atomic_load(p + q, __ATOMIC_RELAXED, __HIP_MEMORY_SCOPE_AGENT);
                    }
            }
            if (ok) break;
            if (--budget <= 0) break;
            __builtin_amdgcn_s_sleep(1);
        }
#pragma unroll
        for (int i = 0; i < 8; ++i) {
            unsigned row = (unsigned)(i * 4 + rq);
            uint2 pk;
            pk.x = (v[i][0] >> 16) | (v[i][1] & 0xffff0000u);
            pk.y = (v[i][2] >> 16) | (v[i][3] & 0xffff0000u);
            unsigned byteoff = row * 1024u + ((halfB + (unsigned)cb * 8u) ^ ((row & 7u) << 4));
            *(uint2*)(Ap + byteoff) = pk;
        }
    };

    for (int t = 0; t < TT; ++t) {
        // ---- half 0 of A (k = 0..255): layer0 = x_t, layer1 = h0[t+1] ----
        if (L0) {
#pragma unroll
            for (int i = 0; i < 8; ++i) {
                unsigned row = (unsigned)(i * 4 + rq);
                float4 f = *(const float4*)(x + (size_t)row * (TT * DD) + (size_t)t * DD + cb * 4);
                uint2 pk;
                pk.x = f2bf(f.x) | (f2bf(f.y) << 16);
                pk.y = f2bf(f.z) | (f2bf(f.w) << 16);
                unsigned byteoff = row * 1024u + (((unsigned)cb * 8u) ^ ((row & 7u) << 4));
                *(uint2*)(Ap + byteoff) = pk;
            }
        } else {
            poll_stage(h0w + (size_t)(t + 1) * HWORDS, (unsigned)(t + 1), 0u);
        }
        // ---- half 1 of A (k = 256..511): own layer's h_prev ----
        if (L0) poll_stage(h0w + (size_t)t * HWORDS, (unsigned)t, 512u);
        else    poll_stage(h1w + (size_t)(t & (RING - 1)) * HWORDS, (unsigned)t, 512u);
        __syncthreads();

        // ---- MFMA: z-tile(16x16) = A(16x512) x B(512x16), B in registers ----
        f32x4 acc = {0.f, 0.f, 0.f, 0.f};
        {
            const unsigned arow = (unsigned)(mt * 16 + (lane & 15));
            const unsigned rbase = arow * 1024u;
            const unsigned asw = (arow & 7u) << 4;
#pragma unroll
            for (int kf = 0; kf < 16; ++kf) {
                unsigned kb = (unsigned)kf * 64u + ((unsigned)(lane >> 4)) * 16u;
                s16x8 a = *(const s16x8*)(Ap + rbase + (kb ^ asw));
                acc = __builtin_amdgcn_mfma_f32_16x16x32_bf16(a, Bfrag[kf], acc, 0, 0, 0);
            }
        }
        // C layout: col = lane&15, row = (lane>>4)*4 + r  [m89-verified]
        {
            const int n = nt * 16 + (lane & 15);
            const int gate = n >> 3;
            const int cl = n & 7;
#pragma unroll
            for (int r = 0; r < 4; ++r) {
                int row = mt * 16 + (lane >> 4) * 4 + r;
                zbuf[gate * 288 + row * 9 + cl] = acc[r];
            }
        }
        __syncthreads();

        // ---- gates (fp32, c in register); publish tagged word, fire-and-forget ----
        {
            float zi = zbuf[0 * 288 + gm * 9 + gj] + bi_;
            float zf = zbuf[1 * 288 + gm * 9 + gj] + bf_;
            float zg = zbuf[2 * 288 + gm * 9 + gj] + bg_;
            float zo = zbuf[3 * 288 + gm * 9 + gj] + bo_;
            c_state = sigm(zf) * c_state + sigm(zi) * tanh_f(zg);
            float h = sigm(zo) * tanh_f(c_state);
            unsigned word = (f2bf(h) << 16) | (unsigned)(t + 1);
            unsigned* dst = (L0 ? h0w + (size_t)(t + 1) * HWORDS
                                : h1w + (size_t)((t + 1) & (RING - 1)) * HWORDS)
                          + gm * 256 + w * HC + gj;
            __hip_atomic_store(dst, word, __ATOMIC_RELAXED, __HIP_MEMORY_SCOPE_AGENT);
        }
        // no barrier needed: next staging writes Ap only (MFMA reads fenced by zbuf barrier),
        // consumers self-synchronize on tags.
    }
}

// out = h1[T] @ Wd + bd   (32x256 @ 256x256, fp32); h1[T] is tagged words in ring slot 0.
__global__ void k_dense(const unsigned* __restrict__ h1last,
                        const float* __restrict__ Wd, const float* __restrict__ bd,
                        float* __restrict__ out)
{
    __shared__ float hs[256];
    const int m = blockIdx.x;
    const int o = threadIdx.x;
    hs[o] = bf2f(h1last[m * 256 + o] >> 16);
    __syncthreads();
    float acc = bd[o];
#pragma unroll 8
    for (int k = 0; k < 256; ++k)
        acc = fmaf(hs[k], Wd[k * 256 + o], acc);
    out[m * 256 + o] = acc;
}

extern "C" void kernel_launch(void* const* d_in, const int* in_sizes, int n_in,
                              void* d_out, int out_size, void* d_ws, size_t ws_size,
                              hipStream_t stream)
{
    const float* x   = (const float*)d_in[0];
    const float* Wi0 = (const float*)d_in[1];
    const float* Wh0 = (const float*)d_in[2];
    const float* b0  = (const float*)d_in[3];
    const float* Wi1 = (const float*)d_in[4];
    const float* Wh1 = (const float*)d_in[5];
    const float* b1  = (const float*)d_in[6];
    const float* Wd  = (const float*)d_in[7];
    const float* bd  = (const float*)d_in[8];
    float* out = (float*)d_out;

    char* ws = (char*)d_ws;
    const size_t h0bytes = (size_t)(TT + 1) * HWORDS * 4;   // full history (layer-1 consumer)
    unsigned* h0w = (unsigned*)ws;
    unsigned* h1w = (unsigned*)(ws + h0bytes);              // 4-slot ring (skew <= 2)

    k_init<<<dim3(HWORDS / 256), dim3(256), 0, stream>>>(h0w, h1w);
    k_scan<<<dim3(64), dim3(256), 0, stream>>>(x, Wi0, Wh0, b0, Wi1, Wh1, b1, h0w, h1w);
    k_dense<<<dim3(32), dim3(256), 0, stream>>>(
        h1w + (size_t)(TT & (RING - 1)) * HWORDS, Wd, bd, out);
}

// Round 3
// 10024.416 us; speedup vs baseline: 1.0706x; 1.0706x over previous
//
#include <hip/hip_runtime.h>
#include <stdint.h>

#define TT 2048
#define DD 256
#define GG 1024
#define HWORDS 8192      // 32 rows x 256 cols tagged words per slot
#define RING 4
#define PROW 1536        // panel row stride bytes: [x(512) | h0(512) | h1(512)]

typedef __attribute__((ext_vector_type(4))) float f32x4;
typedef __attribute__((ext_vector_type(8))) short s16x8;

static __device__ __forceinline__ unsigned f2bf(float f) {
    union { float f; unsigned u; } v; v.f = f;
    return (v.u + 0x7fffu + ((v.u >> 16) & 1u)) >> 16;
}
static __device__ __forceinline__ float bf2f(unsigned b) {
    union { unsigned u; float f; } v; v.u = b << 16;
    return v.f;
}
static __device__ __forceinline__ float sigm(float x) {
    return 1.0f / (1.0f + __expf(-x));
}
static __device__ __forceinline__ float tanh_f(float x) {
    x = fminf(15.0f, fmaxf(-15.0f, x));
    float e = __expf(2.0f * x);
    return (e - 1.0f) / (e + 1.0f);
}

// Zero ring slot 0 of both h buffers (tag 0 == "h after 0 steps = 0").
__global__ void k_init(unsigned* __restrict__ h0, unsigned* __restrict__ h1) {
    int i = blockIdx.x * 256 + threadIdx.x;   // 32 blocks -> 8192 threads
    h0[i] = 0u;
    h1[i] = 0u;
}

// 32 WGs, each owns h-cols [8w, 8w+8) of BOTH layers.
// Cadence c: compute h0[c+1] (c<TT) and h1[c] (c>=1); h0[c] is shared by both layers' panels.
__launch_bounds__(256, 1)
__global__ void k_scan(const float* __restrict__ x,
                       const float* __restrict__ Wi0, const float* __restrict__ Wh0,
                       const float* __restrict__ b0,
                       const float* __restrict__ Wi1, const float* __restrict__ Wh1,
                       const float* __restrict__ b1,
                       unsigned* h0w, unsigned* h1w)
{
    const int tid = threadIdx.x;
    const int w = blockIdx.x;              // 0..31

    __shared__ __align__(16) unsigned char Ap[32 * PROW];   // A panel, XOR-swizzled 16B granules
    __shared__ float zbuf[2 * 4 * 32 * 10];                 // [layer][gate][row][pad10]

    const int lane = tid & 63;
    const int wid = tid >> 6;
    const int mt = wid & 1;        // M-tile (batch rows 16)
    const int nt = wid >> 1;       // N-tile (16 local gate cols)

    // ---- one-time: both layers' weights into registers as MFMA B-fragments ----
    s16x8 Bf0[16], Bf1[16];
    {
        const int jloc = lane & 15;
        const int lcol = nt * 16 + jloc;          // local col: [i0-7 f0-7 | g0-7 o0-7]
        const int gate = lcol >> 3;
        const int jj = lcol & 7;
        const int gcol = gate * 256 + w * 8 + jj;
        const int krow = (lane >> 4) * 8;
#pragma unroll
        for (int kf = 0; kf < 16; ++kf) {
            s16x8 a, b;
#pragma unroll
            for (int j = 0; j < 8; ++j) {
                int k = kf * 32 + krow + j;
                float w0 = (k < 256) ? Wi0[(size_t)k * GG + gcol] : Wh0[(size_t)(k - 256) * GG + gcol];
                float w1 = (k < 256) ? Wi1[(size_t)k * GG + gcol] : Wh1[(size_t)(k - 256) * GG + gcol];
                a[j] = (short)f2bf(w0);
                b[j] = (short)f2bf(w1);
            }
            Bf0[kf] = a; Bf1[kf] = b;
        }
    }

    // gate-update role: thread -> (batch gm, own h-col gj)
    const int gm = tid >> 3;
    const int gj = tid & 7;
    const float b0i = b0[0 * 256 + w * 8 + gj], b0f = b0[1 * 256 + w * 8 + gj];
    const float b0g = b0[2 * 256 + w * 8 + gj], b0o = b0[3 * 256 + w * 8 + gj];
    const float b1i = b1[0 * 256 + w * 8 + gj], b1f = b1[1 * 256 + w * 8 + gj];
    const float b1g = b1[2 * 256 + w * 8 + gj], b1o = b1[3 * 256 + w * 8 + gj];

    // staging role: thread -> 4-col chunk cb, row-quarter rq (rows i*4+rq)
    const int cb = tid & 63;
    const int rq = tid >> 6;

    float c0s = 0.f, c1s = 0.f;
    long long budget = 500000;     // retry-pass bound; untouched in normal runs

    // prologue: prefetch x[0]
    float4 xr[8];
#pragma unroll
    for (int i = 0; i < 8; ++i)
        xr[i] = *(const float4*)(x + (size_t)(i * 4 + rq) * (TT * DD) + cb * 4);

    for (int c = 0; c <= TT; ++c) {
        // ---- stage x[c] (regs -> LDS), then issue prefetch of x[c+1] ----
        if (c < TT) {
#pragma unroll
            for (int i = 0; i < 8; ++i) {
                unsigned row = (unsigned)(i * 4 + rq);
                uint2 pk;
                pk.x = f2bf(xr[i].x) | (f2bf(xr[i].y) << 16);
                pk.y = f2bf(xr[i].z) | (f2bf(xr[i].w) << 16);
                unsigned off = row * PROW + (((unsigned)(cb * 8)) ^ ((row & 7u) << 4));
                *(uint2*)(Ap + off) = pk;
            }
        }
        if (c + 1 < TT) {
#pragma unroll
            for (int i = 0; i < 8; ++i)
                xr[i] = *(const float4*)(x + (size_t)(i * 4 + rq) * (TT * DD) + (size_t)(c + 1) * DD + cb * 4);
        }

        // ---- poll tagged h words (b64 atomics; both slots concurrently) ----
        const unsigned long long* s0 = (const unsigned long long*)(h0w + (size_t)(c & 3) * HWORDS);
        const unsigned long long* s1 = (const unsigned long long*)(h1w + (size_t)((c - 1) & 3) * HWORDS);
        unsigned long long v0[8][2], v1[8][2];
        const unsigned long long msk = 0x0000ffff0000ffffULL;
        const unsigned long long pat0 = 0x0000000100000001ULL * (unsigned long long)(unsigned)c;
        const unsigned long long pat1 = 0x0000000100000001ULL * (unsigned long long)(unsigned)(c - 1);
#pragma unroll
        for (int i = 0; i < 8; ++i) {
            v0[i][0] = __hip_atomic_load(s0 + i * 512 + tid * 2 + 0, __ATOMIC_RELAXED, __HIP_MEMORY_SCOPE_AGENT);
            v0[i][1] = __hip_atomic_load(s0 + i * 512 + tid * 2 + 1, __ATOMIC_RELAXED, __HIP_MEMORY_SCOPE_AGENT);
        }
        if (c >= 1) {
#pragma unroll
            for (int i = 0; i < 8; ++i) {
                v1[i][0] = __hip_atomic_load(s1 + i * 512 + tid * 2 + 0, __ATOMIC_RELAXED, __HIP_MEMORY_SCOPE_AGENT);
                v1[i][1] = __hip_atomic_load(s1 + i * 512 + tid * 2 + 1, __ATOMIC_RELAXED, __HIP_MEMORY_SCOPE_AGENT);
            }
        }
        for (;;) {
            bool ok = true;
#pragma unroll
            for (int i = 0; i < 8; ++i)
#pragma unroll
                for (int j = 0; j < 2; ++j)
                    if ((v0[i][j] & msk) != pat0) {
                        ok = false;
                        v0[i][j] = __hip_atomic_load(s0 + i * 512 + tid * 2 + j, __ATOMIC_RELAXED, __HIP_MEMORY_SCOPE_AGENT);
                    }
            if (c >= 1) {
#pragma unroll
                for (int i = 0; i < 8; ++i)
#pragma unroll
                    for (int j = 0; j < 2; ++j)
                        if ((v1[i][j] & msk) != pat1) {
                            ok = false;
                            v1[i][j] = __hip_atomic_load(s1 + i * 512 + tid * 2 + j, __ATOMIC_RELAXED, __HIP_MEMORY_SCOPE_AGENT);
                        }
            }
            if (ok) break;
            if (--budget <= 0) break;
            __builtin_amdgcn_s_sleep(1);
        }

        // ---- stage h0[c] and h1[c-1] halves into the panel ----
#pragma unroll
        for (int i = 0; i < 8; ++i) {
            unsigned row = (unsigned)(i * 4 + rq);
            unsigned sw = (row & 7u) << 4;
            uint2 pk;
            pk.x = (unsigned)((v0[i][0] >> 16) & 0xffffULL) | ((unsigned)(v0[i][0] >> 48) << 16);
            pk.y = (unsigned)((v0[i][1] >> 16) & 0xffffULL) | ((unsigned)(v0[i][1] >> 48) << 16);
            *(uint2*)(Ap + row * PROW + ((512u + (unsigned)cb * 8u) ^ sw)) = pk;
            if (c >= 1) {
                uint2 pj;
                pj.x = (unsigned)((v1[i][0] >> 16) & 0xffffULL) | ((unsigned)(v1[i][0] >> 48) << 16);
                pj.y = (unsigned)((v1[i][1] >> 16) & 0xffffULL) | ((unsigned)(v1[i][1] >> 48) << 16);
                *(uint2*)(Ap + row * PROW + ((1024u + (unsigned)cb * 8u) ^ sw)) = pj;
            }
        }
        __syncthreads();

        // ---- dual MFMA chains: L0 reads k-bytes [0,1024), L1 reads [512,1536) ----
        f32x4 acc0 = {0.f, 0.f, 0.f, 0.f};
        f32x4 acc1 = {0.f, 0.f, 0.f, 0.f};
        {
            const unsigned arow = (unsigned)(mt * 16 + (lane & 15));
            const unsigned rb = arow * PROW;
            const unsigned asw = (arow & 7u) << 4;
#pragma unroll
            for (int kf = 0; kf < 16; ++kf) {
                unsigned kb = (unsigned)kf * 64u + ((unsigned)(lane >> 4)) * 16u;
                s16x8 a0 = *(const s16x8*)(Ap + rb + (kb ^ asw));
                s16x8 a1 = *(const s16x8*)(Ap + rb + ((kb + 512u) ^ asw));
                acc0 = __builtin_amdgcn_mfma_f32_16x16x32_bf16(a0, Bf0[kf], acc0, 0, 0, 0);
                acc1 = __builtin_amdgcn_mfma_f32_16x16x32_bf16(a1, Bf1[kf], acc1, 0, 0, 0);
            }
        }
        {
            const int n = nt * 16 + (lane & 15);
            const int g = n >> 3;
            const int cl = n & 7;
#pragma unroll
            for (int r = 0; r < 4; ++r) {
                int row = mt * 16 + (lane >> 4) * 4 + r;
                zbuf[g * 320 + row * 10 + cl] = acc0[r];
                zbuf[1280 + g * 320 + row * 10 + cl] = acc1[r];
            }
        }
        __syncthreads();

        // ---- layer-0 gates + publish h0[c+1] first (others wait on it) ----
        if (c < TT) {
            float zi = zbuf[0 * 320 + gm * 10 + gj] + b0i;
            float zf = zbuf[1 * 320 + gm * 10 + gj] + b0f;
            float zg = zbuf[2 * 320 + gm * 10 + gj] + b0g;
            float zo = zbuf[3 * 320 + gm * 10 + gj] + b0o;
            c0s = sigm(zf) * c0s + sigm(zi) * tanh_f(zg);
            float h = sigm(zo) * tanh_f(c0s);
            unsigned word = (f2bf(h) << 16) | (unsigned)(c + 1);
            __hip_atomic_store(h0w + (size_t)((c + 1) & 3) * HWORDS + gm * 256 + w * 8 + gj,
                               word, __ATOMIC_RELAXED, __HIP_MEMORY_SCOPE_AGENT);
        }
        // ---- layer-1 gates + publish h1[c] (store drains under next poll) ----
        if (c >= 1) {
            float zi = zbuf[1280 + 0 * 320 + gm * 10 + gj] + b1i;
            float zf = zbuf[1280 + 1 * 320 + gm * 10 + gj] + b1f;
            float zg = zbuf[1280 + 2 * 320 + gm * 10 + gj] + b1g;
            float zo = zbuf[1280 + 3 * 320 + gm * 10 + gj] + b1o;
            c1s = sigm(zf) * c1s + sigm(zi) * tanh_f(zg);
            float h = sigm(zo) * tanh_f(c1s);
            unsigned word = (f2bf(h) << 16) | (unsigned)c;
            __hip_atomic_store(h1w + (size_t)(c & 3) * HWORDS + gm * 256 + w * 8 + gj,
                               word, __ATOMIC_RELAXED, __HIP_MEMORY_SCOPE_AGENT);
        }
    }
}

// out = h1[T] @ Wd + bd  (32x256 @ 256x256, fp32); h1[T] = tagged words in ring slot TT%4 == 0.
__global__ void k_dense(const unsigned* __restrict__ h1last,
                        const float* __restrict__ Wd, const float* __restrict__ bd,
                        float* __restrict__ out)
{
    __shared__ float hs[256];
    const int m = blockIdx.x;
    const int o = threadIdx.x;
    hs[o] = bf2f(h1last[m * 256 + o] >> 16);
    __syncthreads();
    float acc = bd[o];
#pragma unroll 8
    for (int k = 0; k < 256; ++k)
        acc = fmaf(hs[k], Wd[k * 256 + o], acc);
    out[m * 256 + o] = acc;
}

extern "C" void kernel_launch(void* const* d_in, const int* in_sizes, int n_in,
                              void* d_out, int out_size, void* d_ws, size_t ws_size,
                              hipStream_t stream)
{
    const float* x   = (const float*)d_in[0];
    const float* Wi0 = (const float*)d_in[1];
    const float* Wh0 = (const float*)d_in[2];
    const float* b0  = (const float*)d_in[3];
    const float* Wi1 = (const float*)d_in[4];
    const float* Wh1 = (const float*)d_in[5];
    const float* b1  = (const float*)d_in[6];
    const float* Wd  = (const float*)d_in[7];
    const float* bd  = (const float*)d_in[8];
    float* out = (float*)d_out;

    char* ws = (char*)d_ws;
    const size_t ringbytes = (size_t)RING * HWORDS * 4;   // 128 KB each
    unsigned* h0w = (unsigned*)ws;
    unsigned* h1w = (unsigned*)(ws + ringbytes);

    k_init<<<dim3(32), dim3(256), 0, stream>>>(h0w, h1w);
    k_scan<<<dim3(32), dim3(256), 0, stream>>>(x, Wi0, Wh0, b0, Wi1, Wh1, b1, h0w, h1w);
    k_dense<<<dim3(32), dim3(256), 0, stream>>>(
        h1w + (size_t)(TT & (RING - 1)) * HWORDS, Wd, bd, out);
}

// Round 6
// 9469.734 us; speedup vs baseline: 1.1333x; 1.0586x over previous
//
#include <hip/hip_runtime.h>
#include <stdint.h>

#define TT 2048
#define DD 256
#define GG 1024
#define HWORDS 8192      // 32 rows x 256 cols tagged words per slot
#define RING 4
#define PROW 1536        // panel row stride bytes: [x(512) | h0(512) | h1(512)]

typedef __attribute__((ext_vector_type(4))) float f32x4;
typedef __attribute__((ext_vector_type(8))) short s16x8;

static __device__ __forceinline__ unsigned f2bf(float f) {
    union { float f; unsigned u; } v; v.f = f;
    return (v.u + 0x7fffu + ((v.u >> 16) & 1u)) >> 16;
}
static __device__ __forceinline__ float bf2f(unsigned b) {
    union { unsigned u; float f; } v; v.u = b << 16;
    return v.f;
}
static __device__ __forceinline__ float sigm(float x) {
    return 1.0f / (1.0f + __expf(-x));
}
static __device__ __forceinline__ float tanh_f(float x) {
    x = fminf(15.0f, fmaxf(-15.0f, x));
    float e = __expf(2.0f * x);
    return (e - 1.0f) / (e + 1.0f);
}

// Zero ring slot 0 of both h buffers (tag 0 == "h after 0 steps = 0").
__global__ void k_init(unsigned* __restrict__ h0, unsigned* __restrict__ h1) {
    int i = blockIdx.x * 256 + threadIdx.x;   // 32 blocks -> 8192 = HWORDS
    h0[i] = 0u;
    h1[i] = 0u;
}

// 32 WGs, each owns h-cols [8w, 8w+8) of BOTH layers.
// Cadence c: compute h0[c+1] (c<TT) and h1[c] (c>=1); h0[c] feeds both layers' panels.
// Exchange: tagged words (bf16 value << 16 | step) via relaxed agent-scope atomics.
// Poll discipline: BULK issue -> branch-free check -> BULK re-issue (never per-element
// conditional reloads — those serialize into one memory latency per word).
__launch_bounds__(256, 1)
__global__ void k_scan(const float* __restrict__ x,
                       const float* __restrict__ Wi0, const float* __restrict__ Wh0,
                       const float* __restrict__ b0,
                       const float* __restrict__ Wi1, const float* __restrict__ Wh1,
                       const float* __restrict__ b1,
                       unsigned* h0w, unsigned* h1w)
{
    const int tid = threadIdx.x;
    const int w = blockIdx.x;              // 0..31

    __shared__ __align__(16) unsigned char Ap[32 * PROW];   // A panel, XOR-swizzled 16B granules
    __shared__ float zbuf[2 * 4 * 32 * 10];                 // [layer][gate][row][pad10]

    const int lane = tid & 63;
    const int wid = tid >> 6;
    const int mt = wid & 1;        // M-tile (batch rows 16)
    const int nt = wid >> 1;       // N-tile (16 local gate cols)

    // ---- one-time: both layers' weights into registers as MFMA B-fragments ----
    s16x8 Bf0[16], Bf1[16];
    {
        const int jloc = lane & 15;
        const int lcol = nt * 16 + jloc;          // local col: [i0-7 f0-7 | g0-7 o0-7]
        const int gate = lcol >> 3;
        const int jj = lcol & 7;
        const int gcol = gate * 256 + w * 8 + jj;
        const int krow = (lane >> 4) * 8;
#pragma unroll
        for (int kf = 0; kf < 16; ++kf) {
            s16x8 a, b;
#pragma unroll
            for (int j = 0; j < 8; ++j) {
                int k = kf * 32 + krow + j;
                float w0 = (k < 256) ? Wi0[(size_t)k * GG + gcol] : Wh0[(size_t)(k - 256) * GG + gcol];
                float w1 = (k < 256) ? Wi1[(size_t)k * GG + gcol] : Wh1[(size_t)(k - 256) * GG + gcol];
                a[j] = (short)f2bf(w0);
                b[j] = (short)f2bf(w1);
            }
            Bf0[kf] = a; Bf1[kf] = b;
        }
    }

    // gate-update role: thread -> (batch gm, own h-col gj)
    const int gm = tid >> 3;
    const int gj = tid & 7;
    const float b0i = b0[0 * 256 + w * 8 + gj], b0f = b0[1 * 256 + w * 8 + gj];
    const float b0g = b0[2 * 256 + w * 8 + gj], b0o = b0[3 * 256 + w * 8 + gj];
    const float b1i = b1[0 * 256 + w * 8 + gj], b1f = b1[1 * 256 + w * 8 + gj];
    const float b1g = b1[2 * 256 + w * 8 + gj], b1o = b1[3 * 256 + w * 8 + gj];

    // staging role: thread -> 4-col chunk cb, row-quarter rq (rows i*4+rq)
    const int cb = tid & 63;
    const int rq = tid >> 6;

    float c0s = 0.f, c1s = 0.f;
    long long budget = 500000;     // retry-pass bound; untouched in normal runs

    // prologue: prefetch x[0]
    float4 xr[8];
#pragma unroll
    for (int i = 0; i < 8; ++i)
        xr[i] = *(const float4*)(x + (size_t)(i * 4 + rq) * (TT * DD) + cb * 4);

    for (int c = 0; c <= TT; ++c) {
        const unsigned long long* s0 = (const unsigned long long*)(h0w + (size_t)(c & 3) * HWORDS);
        const unsigned long long* s1 = (const unsigned long long*)(h1w + (size_t)((c - 1) & 3) * HWORDS);
        const unsigned long long msk = 0x0000ffff0000ffffULL;
        const unsigned long long pat0 = 0x0000000100000001ULL * (unsigned long long)(unsigned)c;
        const unsigned long long pat1 = 0x0000000100000001ULL * (unsigned long long)(unsigned)(c - 1);
        unsigned long long v0[8][2], v1[8][2];

        // ---- bulk issue poll loads (latency overlaps the x-staging below) ----
#pragma unroll
        for (int i = 0; i < 8; ++i) {
            v0[i][0] = __hip_atomic_load(s0 + i * 512 + tid * 2 + 0, __ATOMIC_RELAXED, __HIP_MEMORY_SCOPE_AGENT);
            v0[i][1] = __hip_atomic_load(s0 + i * 512 + tid * 2 + 1, __ATOMIC_RELAXED, __HIP_MEMORY_SCOPE_AGENT);
        }
        if (c >= 1) {
#pragma unroll
            for (int i = 0; i < 8; ++i) {
                v1[i][0] = __hip_atomic_load(s1 + i * 512 + tid * 2 + 0, __ATOMIC_RELAXED, __HIP_MEMORY_SCOPE_AGENT);
                v1[i][1] = __hip_atomic_load(s1 + i * 512 + tid * 2 + 1, __ATOMIC_RELAXED, __HIP_MEMORY_SCOPE_AGENT);
            }
        }

        // ---- stage x[c] (regs -> LDS) while poll loads are in flight ----
        if (c < TT) {
#pragma unroll
            for (int i = 0; i < 8; ++i) {
                unsigned row = (unsigned)(i * 4 + rq);
                uint2 pk;
                pk.x = f2bf(xr[i].x) | (f2bf(xr[i].y) << 16);
                pk.y = f2bf(xr[i].z) | (f2bf(xr[i].w) << 16);
                unsigned off = row * PROW + (((unsigned)(cb * 8)) ^ ((row & 7u) << 4));
                *(uint2*)(Ap + off) = pk;
            }
        }

        // ---- branch-free check; on miss, bulk re-issue EVERYTHING ----
        for (;;) {
            unsigned long long d = 0;
#pragma unroll
            for (int i = 0; i < 8; ++i)
                d |= (v0[i][0] ^ pat0) | (v0[i][1] ^ pat0);
            if (c >= 1) {
#pragma unroll
                for (int i = 0; i < 8; ++i)
                    d |= (v1[i][0] ^ pat1) | (v1[i][1] ^ pat1);
            }
            if ((d & msk) == 0) break;
            if (--budget <= 0) break;
            __builtin_amdgcn_s_sleep(1);
#pragma unroll
            for (int i = 0; i < 8; ++i) {
                v0[i][0] = __hip_atomic_load(s0 + i * 512 + tid * 2 + 0, __ATOMIC_RELAXED, __HIP_MEMORY_SCOPE_AGENT);
                v0[i][1] = __hip_atomic_load(s0 + i * 512 + tid * 2 + 1, __ATOMIC_RELAXED, __HIP_MEMORY_SCOPE_AGENT);
            }
            if (c >= 1) {
#pragma unroll
                for (int i = 0; i < 8; ++i) {
                    v1[i][0] = __hip_atomic_load(s1 + i * 512 + tid * 2 + 0, __ATOMIC_RELAXED, __HIP_MEMORY_SCOPE_AGENT);
                    v1[i][1] = __hip_atomic_load(s1 + i * 512 + tid * 2 + 1, __ATOMIC_RELAXED, __HIP_MEMORY_SCOPE_AGENT);
                }
            }
        }

        // ---- unpack h0[c] and h1[c-1] into the panel ----
#pragma unroll
        for (int i = 0; i < 8; ++i) {
            unsigned row = (unsigned)(i * 4 + rq);
            unsigned sw = (row & 7u) << 4;
            uint2 pk;
            pk.x = (unsigned)((v0[i][0] >> 16) & 0xffffULL) | ((unsigned)(v0[i][0] >> 48) << 16);
            pk.y = (unsigned)((v0[i][1] >> 16) & 0xffffULL) | ((unsigned)(v0[i][1] >> 48) << 16);
            *(uint2*)(Ap + row * PROW + ((512u + (unsigned)cb * 8u) ^ sw)) = pk;
            if (c >= 1) {
                uint2 pj;
                pj.x = (unsigned)((v1[i][0] >> 16) & 0xffffULL) | ((unsigned)(v1[i][0] >> 48) << 16);
                pj.y = (unsigned)((v1[i][1] >> 16) & 0xffffULL) | ((unsigned)(v1[i][1] >> 48) << 16);
                *(uint2*)(Ap + row * PROW + ((1024u + (unsigned)cb * 8u) ^ sw)) = pj;
            }
        }

        // ---- prefetch x[c+1] (latency hides under MFMA+gates) ----
        if (c + 1 < TT) {
#pragma unroll
            for (int i = 0; i < 8; ++i)
                xr[i] = *(const float4*)(x + (size_t)(i * 4 + rq) * (TT * DD) + (size_t)(c + 1) * DD + cb * 4);
        }
        __syncthreads();

        // ---- dual MFMA chains: L0 reads k-bytes [0,1024), L1 reads [512,1536) ----
        f32x4 acc0 = {0.f, 0.f, 0.f, 0.f};
        f32x4 acc1 = {0.f, 0.f, 0.f, 0.f};
        {
            const unsigned arow = (unsigned)(mt * 16 + (lane & 15));
            const unsigned rb = arow * PROW;
            const unsigned asw = (arow & 7u) << 4;
#pragma unroll
            for (int kf = 0; kf < 16; ++kf) {
                unsigned kb = (unsigned)kf * 64u + ((unsigned)(lane >> 4)) * 16u;
                s16x8 a0 = *(const s16x8*)(Ap + rb + (kb ^ asw));
                s16x8 a1 = *(const s16x8*)(Ap + rb + ((kb + 512u) ^ asw));
                acc0 = __builtin_amdgcn_mfma_f32_16x16x32_bf16(a0, Bf0[kf], acc0, 0, 0, 0);
                acc1 = __builtin_amdgcn_mfma_f32_16x16x32_bf16(a1, Bf1[kf], acc1, 0, 0, 0);
            }
        }
        {
            const int n = nt * 16 + (lane & 15);
            const int g = n >> 3;
            const int cl = n & 7;
#pragma unroll
            for (int r = 0; r < 4; ++r) {
                int row = mt * 16 + (lane >> 4) * 4 + r;
                zbuf[g * 320 + row * 10 + cl] = acc0[r];
                zbuf[1280 + g * 320 + row * 10 + cl] = acc1[r];
            }
        }
        __syncthreads();

        // ---- layer-0 gates + publish h0[c+1] first (others wait on it) ----
        if (c < TT) {
            float zi = zbuf[0 * 320 + gm * 10 + gj] + b0i;
            float zf = zbuf[1 * 320 + gm * 10 + gj] + b0f;
            float zg = zbuf[2 * 320 + gm * 10 + gj] + b0g;
            float zo = zbuf[3 * 320 + gm * 10 + gj] + b0o;
            c0s = sigm(zf) * c0s + sigm(zi) * tanh_f(zg);
            float h = sigm(zo) * tanh_f(c0s);
            unsigned word = (f2bf(h) << 16) | (unsigned)(c + 1);
            __hip_atomic_store(h0w + (size_t)((c + 1) & 3) * HWORDS + gm * 256 + w * 8 + gj,
                               word, __ATOMIC_RELAXED, __HIP_MEMORY_SCOPE_AGENT);
        }
        // ---- layer-1 gates + publish h1[c] (store drains under next poll) ----
        if (c >= 1) {
            float zi = zbuf[1280 + 0 * 320 + gm * 10 + gj] + b1i;
            float zf = zbuf[1280 + 1 * 320 + gm * 10 + gj] + b1f;
            float zg = zbuf[1280 + 2 * 320 + gm * 10 + gj] + b1g;
            float zo = zbuf[1280 + 3 * 320 + gm * 10 + gj] + b1o;
            c1s = sigm(zf) * c1s + sigm(zi) * tanh_f(zg);
            float h = sigm(zo) * tanh_f(c1s);
            unsigned word = (f2bf(h) << 16) | (unsigned)c;
            __hip_atomic_store(h1w + (size_t)(c & 3) * HWORDS + gm * 256 + w * 8 + gj,
                               word, __ATOMIC_RELAXED, __HIP_MEMORY_SCOPE_AGENT);
        }
    }
}

// out = h1[T] @ Wd + bd  (32x256 @ 256x256, fp32); h1[T] = tagged words in ring slot TT%4 == 0.
__global__ void k_dense(const unsigned* __restrict__ h1last,
                        const float* __restrict__ Wd, const float* __restrict__ bd,
                        float* __restrict__ out)
{
    __shared__ float hs[256];
    const int m = blockIdx.x;
    const int o = threadIdx.x;
    hs[o] = bf2f(h1last[m * 256 + o] >> 16);
    __syncthreads();
    float acc = bd[o];
#pragma unroll 8
    for (int k = 0; k < 256; ++k)
        acc = fmaf(hs[k], Wd[k * 256 + o], acc);
    out[m * 256 + o] = acc;
}

extern "C" void kernel_launch(void* const* d_in, const int* in_sizes, int n_in,
                              void* d_out, int out_size, void* d_ws, size_t ws_size,
                              hipStream_t stream)
{
    const float* x   = (const float*)d_in[0];
    const float* Wi0 = (const float*)d_in[1];
    const float* Wh0 = (const float*)d_in[2];
    const float* b0  = (const float*)d_in[3];
    const float* Wi1 = (const float*)d_in[4];
    const float* Wh1 = (const float*)d_in[5];
    const float* b1  = (const float*)d_in[6];
    const float* Wd  = (const float*)d_in[7];
    const float* bd  = (const float*)d_in[8];
    float* out = (float*)d_out;

    char* ws = (char*)d_ws;
    const size_t ringbytes = (size_t)RING * HWORDS * 4;   // 128 KB each
    unsigned* h0w = (unsigned*)ws;
    unsigned* h1w = (unsigned*)(ws + ringbytes);

    k_init<<<dim3(32), dim3(256), 0, stream>>>(h0w, h1w);
    k_scan<<<dim3(32), dim3(256), 0, stream>>>(x, Wi0, Wh0, b0, Wi1, Wh1, b1, h0w, h1w);
    k_dense<<<dim3(32), dim3(256), 0, stream>>>(
        h1w + (size_t)(TT & (RING - 1)) * HWORDS, Wd, bd, out);
}

// Round 8
// 7721.922 us; speedup vs baseline: 1.3898x; 1.2263x over previous
//
#include <hip/hip_runtime.h>
#include <stdint.h>

#define TT 2048
#define DD 256
#define GG 1024
#define HWORDS 8192      // 32 rows x 256 cols tagged words per slot
#define RING 4
#define PROW 1536        // panel row stride bytes: [x(512) | h0(512) | h1(512)]

typedef __attribute__((ext_vector_type(4))) float f32x4;
typedef __attribute__((ext_vector_type(8))) short s16x8;
typedef __attribute__((ext_vector_type(4))) unsigned u32x4;

static __device__ __forceinline__ unsigned f2bf(float f) {
    union { float f; unsigned u; } v; v.f = f;
    return (v.u + 0x7fffu + ((v.u >> 16) & 1u)) >> 16;
}
static __device__ __forceinline__ float bf2f(unsigned b) {
    union { unsigned u; float f; } v; v.u = b << 16;
    return v.f;
}
static __device__ __forceinline__ float sigm(float x) {
    return 1.0f / (1.0f + __expf(-x));
}
static __device__ __forceinline__ float tanh_f(float x) {
    x = fminf(15.0f, fmaxf(-15.0f, x));
    float e = __expf(2.0f * x);
    return (e - 1.0f) / (e + 1.0f);
}

// Wide system-coherent load: 16B, coalesced across the wave (1KB/instruction),
// bypasses stale local L1/L2 (sc0 sc1). ONE instruction per asm, EARLY-CLOBBER
// output (async writeback must not overlap another statement's address regs).
static __device__ __forceinline__ u32x4 ld16_sys(const unsigned* p) {
    u32x4 r;
    asm volatile("global_load_dwordx4 %0, %1, off sc0 sc1"
                 : "=&v"(r) : "v"(p) : "memory");
    return r;
}
// System-coherent dword store (write through to the coherence point).
static __device__ __forceinline__ void st4_sys(unsigned* p, unsigned d) {
    asm volatile("global_store_dword %0, %1, off sc0 sc1" :: "v"(p), "v"(d) : "memory");
}
#define VWAIT() do { asm volatile("s_waitcnt vmcnt(0)" ::: "memory"); \
                     __builtin_amdgcn_sched_barrier(0); } while (0)

static __device__ __forceinline__ bool tags_ok4(const u32x4 v[8], unsigned tag) {
    unsigned d = 0;
#pragma unroll
    for (int i = 0; i < 8; ++i)
        d |= (v[i][0] ^ tag) | (v[i][1] ^ tag) | (v[i][2] ^ tag) | (v[i][3] ^ tag);
    return (d & 0xffffu) == 0;
}

// Zero ring slot 0 of both h buffers (tag 0 == "h after 0 steps = 0").
__global__ void k_init(unsigned* __restrict__ h0, unsigned* __restrict__ h1) {
    int i = blockIdx.x * 256 + threadIdx.x;   // 32 blocks -> 8192 = HWORDS
    h0[i] = 0u;
    h1[i] = 0u;
}

// 32 WGs, each owns h-cols [8w, 8w+8) of BOTH layers. Same protocol as the
// proven round-6 kernel; ONLY the exchange instructions changed: polls are
// wide coalesced sc0sc1 loads (atomics don't coalesce -> 131K discrete fabric
// transactions/cadence was the suspected floor), publishes are sc0sc1 stores.
__launch_bounds__(256, 1)
__global__ void k_scan(const float* __restrict__ x,
                       const float* __restrict__ Wi0, const float* __restrict__ Wh0,
                       const float* __restrict__ b0,
                       const float* __restrict__ Wi1, const float* __restrict__ Wh1,
                       const float* __restrict__ b1,
                       unsigned* h0w, unsigned* h1w)
{
    const int tid = threadIdx.x;
    const int w = blockIdx.x;              // 0..31

    __shared__ __align__(16) unsigned char Ap[32 * PROW];   // A panel, XOR-swizzled 16B granules
    __shared__ float zbuf[2 * 4 * 32 * 10];                 // [layer][gate][row][pad10]

    const int lane = tid & 63;
    const int wid = tid >> 6;
    const int mt = wid & 1;        // M-tile (batch rows 16)
    const int nt = wid >> 1;       // N-tile (16 local gate cols)

    // ---- one-time: both layers' weights into registers as MFMA B-fragments ----
    s16x8 Bf0[16], Bf1[16];
    {
        const int jloc = lane & 15;
        const int lcol = nt * 16 + jloc;          // local col: [i0-7 f0-7 | g0-7 o0-7]
        const int gate = lcol >> 3;
        const int jj = lcol & 7;
        const int gcol = gate * 256 + w * 8 + jj;
        const int krow = (lane >> 4) * 8;
#pragma unroll
        for (int kf = 0; kf < 16; ++kf) {
            s16x8 a, b;
#pragma unroll
            for (int j = 0; j < 8; ++j) {
                int k = kf * 32 + krow + j;
                float w0 = (k < 256) ? Wi0[(size_t)k * GG + gcol] : Wh0[(size_t)(k - 256) * GG + gcol];
                float w1 = (k < 256) ? Wi1[(size_t)k * GG + gcol] : Wh1[(size_t)(k - 256) * GG + gcol];
                a[j] = (short)f2bf(w0);
                b[j] = (short)f2bf(w1);
            }
            Bf0[kf] = a; Bf1[kf] = b;
        }
    }

    // gate-update role: thread -> (batch gm, own h-col gj)
    const int gm = tid >> 3;
    const int gj = tid & 7;
    const float b0i = b0[0 * 256 + w * 8 + gj], b0f = b0[1 * 256 + w * 8 + gj];
    const float b0g = b0[2 * 256 + w * 8 + gj], b0o = b0[3 * 256 + w * 8 + gj];
    const float b1i = b1[0 * 256 + w * 8 + gj], b1f = b1[1 * 256 + w * 8 + gj];
    const float b1g = b1[2 * 256 + w * 8 + gj], b1o = b1[3 * 256 + w * 8 + gj];

    // staging role: thread -> 4-col chunk cb, row-quarter rq (rows i*4+rq)
    const int cb = tid & 63;
    const int rq = tid >> 6;
    const int hword = gm * 256 + w * 8 + gj;   // this thread's published word index

    float c0s = 0.f, c1s = 0.f;
    long long budget = 500000;     // retry-pass bound; untouched in normal runs

    // prologue: prefetch x[0]
    float4 xr[8];
#pragma unroll
    for (int i = 0; i < 8; ++i)
        xr[i] = *(const float4*)(x + (size_t)(i * 4 + rq) * (TT * DD) + cb * 4);

    for (int c = 0; c <= TT; ++c) {
        // poll sources: thread t covers words [t*4, t*4+4) of each 1024-word quarter
        // (row = i*4 + rq, cols cb*4..cb*4+3 — identical mapping to round 6)
        const unsigned* s0 = h0w + (size_t)(c & 3) * HWORDS + tid * 4;
        const unsigned* s1 = h1w + (size_t)((c - 1) & 3) * HWORDS + tid * 4;
        const unsigned tag0 = (unsigned)c;
        const unsigned tag1 = (unsigned)(c - 1);
        u32x4 v0[8], v1[8];

        // ---- bulk issue wide poll loads (latency overlaps the x-staging below) ----
#pragma unroll
        for (int i = 0; i < 8; ++i) v0[i] = ld16_sys(s0 + i * 1024);
        if (c >= 1) {
#pragma unroll
            for (int i = 0; i < 8; ++i) v1[i] = ld16_sys(s1 + i * 1024);
        }

        // ---- stage x[c] (regs -> LDS) while poll loads are in flight ----
        if (c < TT) {
#pragma unroll
            for (int i = 0; i < 8; ++i) {
                unsigned row = (unsigned)(i * 4 + rq);
                uint2 pk;
                pk.x = f2bf(xr[i].x) | (f2bf(xr[i].y) << 16);
                pk.y = f2bf(xr[i].z) | (f2bf(xr[i].w) << 16);
                unsigned off = row * PROW + (((unsigned)(cb * 8)) ^ ((row & 7u) << 4));
                *(uint2*)(Ap + off) = pk;
            }
        }
        VWAIT();

        // ---- branch-free check; on miss, bulk re-issue EVERYTHING ----
        for (;;) {
            bool ok = tags_ok4(v0, tag0) && (c == 0 || tags_ok4(v1, tag1));
            if (ok) break;
            if (--budget <= 0) break;
            __builtin_amdgcn_s_sleep(1);
#pragma unroll
            for (int i = 0; i < 8; ++i) v0[i] = ld16_sys(s0 + i * 1024);
            if (c >= 1) {
#pragma unroll
                for (int i = 0; i < 8; ++i) v1[i] = ld16_sys(s1 + i * 1024);
            }
            VWAIT();
        }

        // ---- unpack h0[c] and h1[c-1] into the panel ----
#pragma unroll
        for (int i = 0; i < 8; ++i) {
            unsigned row = (unsigned)(i * 4 + rq);
            unsigned sw = (row & 7u) << 4;
            uint2 pk;
            pk.x = (v0[i][0] >> 16) | (v0[i][1] & 0xffff0000u);
            pk.y = (v0[i][2] >> 16) | (v0[i][3] & 0xffff0000u);
            *(uint2*)(Ap + row * PROW + ((512u + (unsigned)cb * 8u) ^ sw)) = pk;
            if (c >= 1) {
                uint2 pj;
                pj.x = (v1[i][0] >> 16) | (v1[i][1] & 0xffff0000u);
                pj.y = (v1[i][2] >> 16) | (v1[i][3] & 0xffff0000u);
                *(uint2*)(Ap + row * PROW + ((1024u + (unsigned)cb * 8u) ^ sw)) = pj;
            }
        }

        // ---- prefetch x[c+1] (latency hides under MFMA+gates) ----
        if (c + 1 < TT) {
#pragma unroll
            for (int i = 0; i < 8; ++i)
                xr[i] = *(const float4*)(x + (size_t)(i * 4 + rq) * (TT * DD) + (size_t)(c + 1) * DD + cb * 4);
        }
        __syncthreads();

        // ---- dual MFMA chains: L0 reads k-bytes [0,1024), L1 reads [512,1536) ----
        f32x4 acc0 = {0.f, 0.f, 0.f, 0.f};
        f32x4 acc1 = {0.f, 0.f, 0.f, 0.f};
        {
            const unsigned arow = (unsigned)(mt * 16 + (lane & 15));
            const unsigned rb = arow * PROW;
            const unsigned asw = (arow & 7u) << 4;
#pragma unroll
            for (int kf = 0; kf < 16; ++kf) {
                unsigned kb = (unsigned)kf * 64u + ((unsigned)(lane >> 4)) * 16u;
                s16x8 a0 = *(const s16x8*)(Ap + rb + (kb ^ asw));
                s16x8 a1 = *(const s16x8*)(Ap + rb + ((kb + 512u) ^ asw));
                acc0 = __builtin_amdgcn_mfma_f32_16x16x32_bf16(a0, Bf0[kf], acc0, 0, 0, 0);
                acc1 = __builtin_amdgcn_mfma_f32_16x16x32_bf16(a1, Bf1[kf], acc1, 0, 0, 0);
            }
        }
        {
            const int n = nt * 16 + (lane & 15);
            const int g = n >> 3;
            const int cl = n & 7;
#pragma unroll
            for (int r = 0; r < 4; ++r) {
                int row = mt * 16 + (lane >> 4) * 4 + r;
                zbuf[g * 320 + row * 10 + cl] = acc0[r];
                zbuf[1280 + g * 320 + row * 10 + cl] = acc1[r];
            }
        }
        __syncthreads();

        // ---- layer-0 gates + publish h0[c+1] first (others wait on it) ----
        if (c < TT) {
            float zi = zbuf[0 * 320 + gm * 10 + gj] + b0i;
            float zf = zbuf[1 * 320 + gm * 10 + gj] + b0f;
            float zg = zbuf[2 * 320 + gm * 10 + gj] + b0g;
            float zo = zbuf[3 * 320 + gm * 10 + gj] + b0o;
            c0s = sigm(zf) * c0s + sigm(zi) * tanh_f(zg);
            float h = sigm(zo) * tanh_f(c0s);
            unsigned word = (f2bf(h) << 16) | (unsigned)(c + 1);
            st4_sys(h0w + (size_t)((c + 1) & 3) * HWORDS + hword, word);
        }
        // ---- layer-1 gates + publish h1[c] (store drains under next poll) ----
        if (c >= 1) {
            float zi = zbuf[1280 + 0 * 320 + gm * 10 + gj] + b1i;
            float zf = zbuf[1280 + 1 * 320 + gm * 10 + gj] + b1f;
            float zg = zbuf[1280 + 2 * 320 + gm * 10 + gj] + b1g;
            float zo = zbuf[1280 + 3 * 320 + gm * 10 + gj] + b1o;
            c1s = sigm(zf) * c1s + sigm(zi) * tanh_f(zg);
            float h = sigm(zo) * tanh_f(c1s);
            unsigned word = (f2bf(h) << 16) | (unsigned)c;
            st4_sys(h1w + (size_t)(c & 3) * HWORDS + hword, word);
        }
    }
}

// out = h1[T] @ Wd + bd  (32x256 @ 256x256, fp32); h1[T] = tagged words in ring slot TT%4 == 0.
__global__ void k_dense(const unsigned* __restrict__ h1last,
                        const float* __restrict__ Wd, const float* __restrict__ bd,
                        float* __restrict__ out)
{
    __shared__ float hs[256];
    const int m = blockIdx.x;
    const int o = threadIdx.x;
    hs[o] = bf2f(h1last[m * 256 + o] >> 16);
    __syncthreads();
    float acc = bd[o];
#pragma unroll 8
    for (int k = 0; k < 256; ++k)
        acc = fmaf(hs[k], Wd[k * 256 + o], acc);
    out[m * 256 + o] = acc;
}

extern "C" void kernel_launch(void* const* d_in, const int* in_sizes, int n_in,
                              void* d_out, int out_size, void* d_ws, size_t ws_size,
                              hipStream_t stream)
{
    const float* x   = (const float*)d_in[0];
    const float* Wi0 = (const float*)d_in[1];
    const float* Wh0 = (const float*)d_in[2];
    const float* b0  = (const float*)d_in[3];
    const float* Wi1 = (const float*)d_in[4];
    const float* Wh1 = (const float*)d_in[5];
    const float* b1  = (const float*)d_in[6];
    const float* Wd  = (const float*)d_in[7];
    const float* bd  = (const float*)d_in[8];
    float* out = (float*)d_out;

    char* ws = (char*)d_ws;
    const size_t ringbytes = (size_t)RING * HWORDS * 4;   // 128 KB each
    unsigned* h0w = (unsigned*)ws;
    unsigned* h1w = (unsigned*)(ws + ringbytes);

    k_init<<<dim3(32), dim3(256), 0, stream>>>(h0w, h1w);
    k_scan<<<dim3(32), dim3(256), 0, stream>>>(x, Wi0, Wh0, b0, Wi1, Wh1, b1, h0w, h1w);
    k_dense<<<dim3(32), dim3(256), 0, stream>>>(
        h1w + (size_t)(TT & (RING - 1)) * HWORDS, Wd, bd, out);
}

// Round 9
// 6159.016 us; speedup vs baseline: 1.7424x; 1.2538x over previous
//
#include <hip/hip_runtime.h>
#include <stdint.h>

#define TT 2048
#define DD 256
#define GG 1024
#define HWORDS 8192      // 32 rows x 256 cols tagged words per slot
#define RING 4
#define PROW 1536        // panel row stride bytes: [x(512) | h0(512) | h1(512)]

typedef __attribute__((ext_vector_type(4))) float f32x4;
typedef __attribute__((ext_vector_type(8))) short s16x8;
typedef __attribute__((ext_vector_type(4))) unsigned u32x4;

static __device__ __forceinline__ unsigned f2bf(float f) {
    union { float f; unsigned u; } v; v.f = f;
    return (v.u + 0x7fffu + ((v.u >> 16) & 1u)) >> 16;
}
static __device__ __forceinline__ float bf2f(unsigned b) {
    union { unsigned u; float f; } v; v.u = b << 16;
    return v.f;
}
static __device__ __forceinline__ float sigm(float x) {
    return 1.0f / (1.0f + __expf(-x));
}
static __device__ __forceinline__ float tanh_f(float x) {
    x = fminf(15.0f, fmaxf(-15.0f, x));
    float e = __expf(2.0f * x);
    return (e - 1.0f) / (e + 1.0f);
}

// Wide system-coherent poll load (16B, coalesced, bypasses stale local L1/L2).
static __device__ __forceinline__ u32x4 ld16_sys(const unsigned* p) {
    u32x4 r;
    asm volatile("global_load_dwordx4 %0, %1, off sc0 sc1"
                 : "=&v"(r) : "v"(p) : "memory");
    return r;
}
// Plain wide load (x prefetch) — in asm so WE control vmcnt issue order.
static __device__ __forceinline__ u32x4 ld16(const unsigned* p) {
    u32x4 r;
    asm volatile("global_load_dwordx4 %0, %1, off"
                 : "=&v"(r) : "v"(p) : "memory");
    return r;
}
// System-coherent dword publish store.
static __device__ __forceinline__ void st4_sys(unsigned* p, unsigned d) {
    asm volatile("global_store_dword %0, %1, off sc0 sc1" :: "v"(p), "v"(d) : "memory");
}

// Counted waits (in-order vmcnt retirement; issue order is asm-pinned).
#define VW(n) do { asm volatile("s_waitcnt vmcnt(" #n ")" ::: "memory"); \
                   __builtin_amdgcn_sched_barrier(0); } while (0)
// LDS-only barrier: does NOT drain vmcnt — prefetches/publishes stay in flight.
#define LBAR() do { asm volatile("s_waitcnt lgkmcnt(0)\n\ts_barrier" ::: "memory"); \
                    __builtin_amdgcn_sched_barrier(0); } while (0)

static __device__ __forceinline__ bool tags_ok4(const u32x4 v[8], unsigned tag) {
    unsigned d = 0;
#pragma unroll
    for (int i = 0; i < 8; ++i)
        d |= (v[i][0] ^ tag) | (v[i][1] ^ tag) | (v[i][2] ^ tag) | (v[i][3] ^ tag);
    return (d & 0xffffu) == 0;
}

// Zero ring slot 0 of both h buffers (tag 0 == "h after 0 steps = 0").
__global__ void k_init(unsigned* __restrict__ h0, unsigned* __restrict__ h1) {
    int i = blockIdx.x * 256 + threadIdx.x;   // 32 blocks -> 8192 = HWORDS
    h0[i] = 0u;
    h1[i] = 0u;
}

// 32 WGs, each owns h-cols [8w, 8w+8) of BOTH layers. Round-8 protocol, new schedule:
//  - counted vmcnt: VW(8) waits only the 8 h0 polls (x prefetch rides through);
//    VW(1) waits h1 polls but NOT the h0-publish ack. Tail cadences where counts
//    would under-wait are caught by the tag-retry (which uses vmcnt(0)).
//  - LDS-only barriers (5x LBAR): no vmcnt drains on the critical path.
//  - split MFMA: phase A (L0 x-half) hides h0 poll latency; h0[c+1] publishes
//    right after phase B; L1's poll+MFMA+gates sit off the h0 recurrence path.
__launch_bounds__(256, 1)
__global__ void k_scan(const float* __restrict__ x,
                       const float* __restrict__ Wi0, const float* __restrict__ Wh0,
                       const float* __restrict__ b0,
                       const float* __restrict__ Wi1, const float* __restrict__ Wh1,
                       const float* __restrict__ b1,
                       unsigned* h0w, unsigned* h1w)
{
    const int tid = threadIdx.x;
    const int w = blockIdx.x;              // 0..31

    __shared__ __align__(16) unsigned char Ap[32 * PROW];   // A panel, XOR-swizzled 16B granules
    __shared__ float zbuf[2 * 4 * 32 * 10];                 // [layer][gate][row][pad10]

    const int lane = tid & 63;
    const int wid = tid >> 6;
    const int mt = wid & 1;        // M-tile (batch rows 16)
    const int nt = wid >> 1;       // N-tile (16 local gate cols)

    // ---- one-time: both layers' weights into registers as MFMA B-fragments ----
    s16x8 Bf0[16], Bf1[16];
    {
        const int jloc = lane & 15;
        const int lcol = nt * 16 + jloc;          // local col: [i0-7 f0-7 | g0-7 o0-7]
        const int gate = lcol >> 3;
        const int jj = lcol & 7;
        const int gcol = gate * 256 + w * 8 + jj;
        const int krow = (lane >> 4) * 8;
#pragma unroll
        for (int kf = 0; kf < 16; ++kf) {
            s16x8 a, b;
#pragma unroll
            for (int j = 0; j < 8; ++j) {
                int k = kf * 32 + krow + j;
                float w0 = (k < 256) ? Wi0[(size_t)k * GG + gcol] : Wh0[(size_t)(k - 256) * GG + gcol];
                float w1 = (k < 256) ? Wi1[(size_t)k * GG + gcol] : Wh1[(size_t)(k - 256) * GG + gcol];
                a[j] = (short)f2bf(w0);
                b[j] = (short)f2bf(w1);
            }
            Bf0[kf] = a; Bf1[kf] = b;
        }
    }

    // gate-update role: thread -> (batch gm, own h-col gj)
    const int gm = tid >> 3;
    const int gj = tid & 7;
    const float b0i = b0[0 * 256 + w * 8 + gj], b0f = b0[1 * 256 + w * 8 + gj];
    const float b0g = b0[2 * 256 + w * 8 + gj], b0o = b0[3 * 256 + w * 8 + gj];
    const float b1i = b1[0 * 256 + w * 8 + gj], b1f = b1[1 * 256 + w * 8 + gj];
    const float b1g = b1[2 * 256 + w * 8 + gj], b1o = b1[3 * 256 + w * 8 + gj];

    // staging role: thread -> 4-col chunk cb, row-quarter rq (rows i*4+rq)
    const int cb = tid & 63;
    const int rq = tid >> 6;
    const int hword = gm * 256 + w * 8 + gj;   // this thread's published word index

    const unsigned arow = (unsigned)(mt * 16 + (lane & 15));
    const unsigned rb = arow * PROW;
    const unsigned asw = (arow & 7u) << 4;

    float c0s = 0.f, c1s = 0.f;
    long long budget = 500000;     // retry-pass bound; untouched in normal runs

    // prologue: prefetch x[0] (asm loads; drained before first use)
    u32x4 xr[8];
#pragma unroll
    for (int i = 0; i < 8; ++i)
        xr[i] = ld16((const unsigned*)(x + (size_t)(i * 4 + rq) * (TT * DD) + cb * 4));
    VW(0);

    for (int c = 0; c <= TT; ++c) {
        const unsigned tag0 = (unsigned)c;
        const unsigned tag1 = (unsigned)(c - 1);
        const unsigned* s0 = h0w + (size_t)(c & 3) * HWORDS + tid * 4;
        const unsigned* s1 = h1w + (size_t)((c - 1) & 3) * HWORDS + tid * 4;

        // ---- stage x[c] (regs -> LDS); xr guaranteed drained (prev VW(1)/prologue) ----
        if (c < TT) {
#pragma unroll
            for (int i = 0; i < 8; ++i) {
                unsigned row = (unsigned)(i * 4 + rq);
                uint2 pk;
                pk.x = f2bf(__uint_as_float(xr[i][0])) | (f2bf(__uint_as_float(xr[i][1])) << 16);
                pk.y = f2bf(__uint_as_float(xr[i][2])) | (f2bf(__uint_as_float(xr[i][3])) << 16);
                *(uint2*)(Ap + row * PROW + (((unsigned)(cb * 8)) ^ ((row & 7u) << 4))) = pk;
            }
        }

        // ---- issue h0 polls, then x[c+1] prefetch (issue order pins vmcnt counting) ----
        u32x4 v0[8];
#pragma unroll
        for (int i = 0; i < 8; ++i) v0[i] = ld16_sys(s0 + i * 1024);
        if (c + 1 < TT) {
#pragma unroll
            for (int i = 0; i < 8; ++i)
                xr[i] = ld16((const unsigned*)(x + (size_t)(i * 4 + rq) * (TT * DD)
                                               + (size_t)(c + 1) * DD + cb * 4));
        }

        LBAR();   // B1: x panel staged (polls + prefetch in flight)

        // ---- phase A: L0 x-half MFMA (reads [0,512)) — hides h0 poll latency ----
        f32x4 acc0 = {0.f, 0.f, 0.f, 0.f};
#pragma unroll
        for (int kf = 0; kf < 8; ++kf) {
            unsigned kb = (unsigned)kf * 64u + ((unsigned)(lane >> 4)) * 16u;
            s16x8 a0 = *(const s16x8*)(Ap + rb + (kb ^ asw));
            acc0 = __builtin_amdgcn_mfma_f32_16x16x32_bf16(a0, Bf0[kf], acc0, 0, 0, 0);
        }

        // ---- wait h0 polls only (x prefetch, newest 8, stays in flight) ----
        if (c + 1 < TT) VW(8); else VW(0);
        while (!tags_ok4(v0, tag0)) {
            if (--budget <= 0) break;
            __builtin_amdgcn_s_sleep(1);
#pragma unroll
            for (int i = 0; i < 8; ++i) v0[i] = ld16_sys(s0 + i * 1024);
            VW(0);
        }

        // ---- unpack h0[c] -> panel [512,1024); then issue h1 polls ----
#pragma unroll
        for (int i = 0; i < 8; ++i) {
            unsigned row = (unsigned)(i * 4 + rq);
            uint2 pk;
            pk.x = (v0[i][0] >> 16) | (v0[i][1] & 0xffff0000u);
            pk.y = (v0[i][2] >> 16) | (v0[i][3] & 0xffff0000u);
            *(uint2*)(Ap + row * PROW + ((512u + (unsigned)cb * 8u) ^ ((row & 7u) << 4))) = pk;
        }
        u32x4 v1[8];
        if (c >= 1) {
#pragma unroll
            for (int i = 0; i < 8; ++i) v1[i] = ld16_sys(s1 + i * 1024);
        }

        LBAR();   // B2: h0 panel ready

        // ---- phase B: L0 h-half + L1 x-half (both read [512,1024)) ----
        f32x4 acc1 = {0.f, 0.f, 0.f, 0.f};
#pragma unroll
        for (int kf = 8; kf < 16; ++kf) {
            unsigned kb = (unsigned)kf * 64u + ((unsigned)(lane >> 4)) * 16u;
            s16x8 a0 = *(const s16x8*)(Ap + rb + (kb ^ asw));
            acc0 = __builtin_amdgcn_mfma_f32_16x16x32_bf16(a0, Bf0[kf], acc0, 0, 0, 0);
            s16x8 a1 = *(const s16x8*)(Ap + rb + (((kb - 512u) + 512u) ^ asw));
            acc1 = __builtin_amdgcn_mfma_f32_16x16x32_bf16(a1, Bf1[kf - 8], acc1, 0, 0, 0);
        }
        {
            const int n = nt * 16 + (lane & 15);
            const int g = n >> 3, cl = n & 7;
#pragma unroll
            for (int r = 0; r < 4; ++r)
                zbuf[g * 320 + (mt * 16 + (lane >> 4) * 4 + r) * 10 + cl] = acc0[r];
        }

        LBAR();   // B3: zbuf0 ready (all waves past phase B)

        // ---- gates L0 + publish h0[c+1] IMMEDIATELY (the critical recurrence) ----
        if (c < TT) {
            float zi = zbuf[0 * 320 + gm * 10 + gj] + b0i;
            float zf = zbuf[1 * 320 + gm * 10 + gj] + b0f;
            float zg = zbuf[2 * 320 + gm * 10 + gj] + b0g;
            float zo = zbuf[3 * 320 + gm * 10 + gj] + b0o;
            c0s = sigm(zf) * c0s + sigm(zi) * tanh_f(zg);
            float h = sigm(zo) * tanh_f(c0s);
            st4_sys(h0w + (size_t)((c + 1) & 3) * HWORDS + hword,
                    (f2bf(h) << 16) | (unsigned)(c + 1));
        }

        // ---- wait h1 polls + x prefetch (h0-publish ack, newest, NOT waited) ----
        VW(1);
        if (c >= 1) {
            while (!tags_ok4(v1, tag1)) {
                if (--budget <= 0) break;
                __builtin_amdgcn_s_sleep(1);
#pragma unroll
                for (int i = 0; i < 8; ++i) v1[i] = ld16_sys(s1 + i * 1024);
                VW(0);
            }
            // unpack h1[c-1] -> panel [1024,1536)
#pragma unroll
            for (int i = 0; i < 8; ++i) {
                unsigned row = (unsigned)(i * 4 + rq);
                uint2 pj;
                pj.x = (v1[i][0] >> 16) | (v1[i][1] & 0xffff0000u);
                pj.y = (v1[i][2] >> 16) | (v1[i][3] & 0xffff0000u);
                *(uint2*)(Ap + row * PROW + ((1024u + (unsigned)cb * 8u) ^ ((row & 7u) << 4))) = pj;
            }
        }

        LBAR();   // B4: h1 panel ready

        // ---- phase C: L1 h-half (reads [1024,1536)) ----
#pragma unroll
        for (int kf = 8; kf < 16; ++kf) {
            unsigned kb = (unsigned)kf * 64u + ((unsigned)(lane >> 4)) * 16u + 512u;
            s16x8 a1 = *(const s16x8*)(Ap + rb + (kb ^ asw));
            acc1 = __builtin_amdgcn_mfma_f32_16x16x32_bf16(a1, Bf1[kf], acc1, 0, 0, 0);
        }
        {
            const int n = nt * 16 + (lane & 15);
            const int g = n >> 3, cl = n & 7;
#pragma unroll
            for (int r = 0; r < 4; ++r)
                zbuf[1280 + g * 320 + (mt * 16 + (lane >> 4) * 4 + r) * 10 + cl] = acc1[r];
        }

        LBAR();   // B5: zbuf1 ready

        // ---- gates L1 + publish h1[c] ----
        if (c >= 1) {
            float zi = zbuf[1280 + 0 * 320 + gm * 10 + gj] + b1i;
            float zf = zbuf[1280 + 1 * 320 + gm * 10 + gj] + b1f;
            float zg = zbuf[1280 + 2 * 320 + gm * 10 + gj] + b1g;
            float zo = zbuf[1280 + 3 * 320 + gm * 10 + gj] + b1o;
            c1s = sigm(zf) * c1s + sigm(zi) * tanh_f(zg);
            float h = sigm(zo) * tanh_f(c1s);
            st4_sys(h1w + (size_t)(c & 3) * HWORDS + hword,
                    (f2bf(h) << 16) | (unsigned)c);
        }
    }
}

// out = h1[T] @ Wd + bd  (32x256 @ 256x256, fp32); h1[T] = tagged words in ring slot TT%4 == 0.
__global__ void k_dense(const unsigned* __restrict__ h1last,
                        const float* __restrict__ Wd, const float* __restrict__ bd,
                        float* __restrict__ out)
{
    __shared__ float hs[256];
    const int m = blockIdx.x;
    const int o = threadIdx.x;
    hs[o] = bf2f(h1last[m * 256 + o] >> 16);
    __syncthreads();
    float acc = bd[o];
#pragma unroll 8
    for (int k = 0; k < 256; ++k)
        acc = fmaf(hs[k], Wd[k * 256 + o], acc);
    out[m * 256 + o] = acc;
}

extern "C" void kernel_launch(void* const* d_in, const int* in_sizes, int n_in,
                              void* d_out, int out_size, void* d_ws, size_t ws_size,
                              hipStream_t stream)
{
    const float* x   = (const float*)d_in[0];
    const float* Wi0 = (const float*)d_in[1];
    const float* Wh0 = (const float*)d_in[2];
    const float* b0  = (const float*)d_in[3];
    const float* Wi1 = (const float*)d_in[4];
    const float* Wh1 = (const float*)d_in[5];
    const float* b1  = (const float*)d_in[6];
    const float* Wd  = (const float*)d_in[7];
    const float* bd  = (const float*)d_in[8];
    float* out = (float*)d_out;

    char* ws = (char*)d_ws;
    const size_t ringbytes = (size_t)RING * HWORDS * 4;   // 128 KB each
    unsigned* h0w = (unsigned*)ws;
    unsigned* h1w = (unsigned*)(ws + ringbytes);

    k_init<<<dim3(32), dim3(256), 0, stream>>>(h0w, h1w);
    k_scan<<<dim3(32), dim3(256), 0, stream>>>(x, Wi0, Wh0, b0, Wi1, Wh1, b1, h0w, h1w);
    k_dense<<<dim3(32), dim3(256), 0, stream>>>(
        h1w + (size_t)(TT & (RING - 1)) * HWORDS, Wd, bd, out);
}

// Round 10
// 4938.663 us; speedup vs baseline: 2.1730x; 1.2471x over previous
//
#include <hip/hip_runtime.h>
#include <stdint.h>

#define TT 2048
#define DD 256
#define GG 1024
#define HWORDS 8192      // one slot: 32 rows x 256 cols tagged words
#define RING0 64         // h0 ring slots (2MB; big => throttle is amortized)
#define RING1 4          // h1 ring slots
#define PROW 1024        // panel row stride bytes: [in(512) | h(512)]

typedef __attribute__((ext_vector_type(4))) float f32x4;
typedef __attribute__((ext_vector_type(8))) short s16x8;
typedef __attribute__((ext_vector_type(4))) unsigned u32x4;

static __device__ __forceinline__ unsigned f2bf(float f) {
    union { float f; unsigned u; } v; v.f = f;
    return (v.u + 0x7fffu + ((v.u >> 16) & 1u)) >> 16;
}
static __device__ __forceinline__ float bf2f(unsigned b) {
    union { unsigned u; float f; } v; v.u = b << 16;
    return v.f;
}
static __device__ __forceinline__ float sigm(float x) {
    return 1.0f / (1.0f + __expf(-x));
}
static __device__ __forceinline__ float tanh_f(float x) {
    x = fminf(15.0f, fmaxf(-15.0f, x));
    float e = __expf(2.0f * x);
    return (e - 1.0f) / (e + 1.0f);
}

// Wide system-coherent poll load (16B, coalesced, bypasses stale local L1/L2).
static __device__ __forceinline__ u32x4 ld16_sys(const unsigned* p) {
    u32x4 r;
    asm volatile("global_load_dwordx4 %0, %1, off sc0 sc1"
                 : "=&v"(r) : "v"(p) : "memory");
    return r;
}
// Plain wide load (x prefetch) — asm so WE control vmcnt issue order.
static __device__ __forceinline__ u32x4 ld16(const unsigned* p) {
    u32x4 r;
    asm volatile("global_load_dwordx4 %0, %1, off"
                 : "=&v"(r) : "v"(p) : "memory");
    return r;
}
// System-coherent dword publish store.
static __device__ __forceinline__ void st4_sys(unsigned* p, unsigned d) {
    asm volatile("global_store_dword %0, %1, off sc0 sc1" :: "v"(p), "v"(d) : "memory");
}

#define VW(n) do { asm volatile("s_waitcnt vmcnt(" #n ")" ::: "memory"); \
                   __builtin_amdgcn_sched_barrier(0); } while (0)
// LDS-only barrier: does NOT drain vmcnt.
#define LBAR() do { asm volatile("s_waitcnt lgkmcnt(0)\n\ts_barrier" ::: "memory"); \
                    __builtin_amdgcn_sched_barrier(0); } while (0)

static __device__ __forceinline__ bool tags_ok4(const u32x4 v[8], unsigned tag) {
    unsigned d = 0;
#pragma unroll
    for (int i = 0; i < 8; ++i)
        d |= (v[i][0] ^ tag) | (v[i][1] ^ tag) | (v[i][2] ^ tag) | (v[i][3] ^ tag);
    return (d & 0xffffu) == 0;
}

// Zero BOTH rings fully every launch (tag 0 == unpublished; replay-safe semantics).
__global__ void k_init(unsigned* __restrict__ h0, unsigned* __restrict__ h1) {
    unsigned i = blockIdx.x * 256 + threadIdx.x;   // grid 2048 -> 524288 words
    h0[i] = 0u;                                    // 64 slots
    if (i < RING1 * HWORDS) h1[i] = 0u;            // 4 slots
}

// Two crews of 32 WGs in ONE kernel (sequential launches would deadlock):
//  blocks 0..31  = L0 crew: h0[c+1] = LSTM0(x[c], h0[c]); publishes into 64-slot ring.
//  blocks 32..63 = L1 crew: h1[c+1] = LSTM1(h0[c+1], h1[c]); h0 is feed-forward
//                  (polls prefetched cross-cadence), h1 is the recurrent all-to-all.
// L0 throttles on h1-ring tags (proof of consumption) so the 64-slot ring never
// overruns; watermark caching makes the check ~1 per 60 cadences.
__launch_bounds__(256, 1)
__global__ void k_scan(const float* __restrict__ x,
                       const float* __restrict__ Wi0, const float* __restrict__ Wh0,
                       const float* __restrict__ b0,
                       const float* __restrict__ Wi1, const float* __restrict__ Wh1,
                       const float* __restrict__ b1,
                       unsigned* h0w, unsigned* h1w)
{
    const int tid = threadIdx.x;
    const bool isL0 = (blockIdx.x < 32);
    const int w = blockIdx.x & 31;

    const float* Wi = isL0 ? Wi0 : Wi1;
    const float* Wh = isL0 ? Wh0 : Wh1;
    const float* bb = isL0 ? b0 : b1;

    __shared__ __align__(16) unsigned char Ap[32 * PROW];   // [in 512B | h 512B] per row, XOR-swizzled
    __shared__ float zbuf[4 * 32 * 10];                     // [gate][row][pad10]

    const int lane = tid & 63;
    const int wid = tid >> 6;
    const int mt = wid & 1;        // M-tile (batch rows 16)
    const int nt = wid >> 1;       // N-tile (16 local gate cols)

    // ---- one-time: this layer's weights as MFMA B-fragments (64 VGPRs) ----
    s16x8 Bf[16];
    {
        const int jloc = lane & 15;
        const int lcol = nt * 16 + jloc;          // local col: [i0-7 f0-7 | g0-7 o0-7]
        const int gate = lcol >> 3;
        const int jj = lcol & 7;
        const int gcol = gate * 256 + w * 8 + jj;
        const int krow = (lane >> 4) * 8;
#pragma unroll
        for (int kf = 0; kf < 16; ++kf) {
            s16x8 a;
#pragma unroll
            for (int j = 0; j < 8; ++j) {
                int k = kf * 32 + krow + j;
                float wv = (k < 256) ? Wi[(size_t)k * GG + gcol] : Wh[(size_t)(k - 256) * GG + gcol];
                a[j] = (short)f2bf(wv);
            }
            Bf[kf] = a;
        }
    }

    const int gm = tid >> 3;       // gate-update role: (batch gm, own h-col gj)
    const int gj = tid & 7;
    const float bi_ = bb[0 * 256 + w * 8 + gj], bf_ = bb[1 * 256 + w * 8 + gj];
    const float bg_ = bb[2 * 256 + w * 8 + gj], bo_ = bb[3 * 256 + w * 8 + gj];

    const int cb = tid & 63;       // staging role: 4-col chunk cb, row-quarter rq
    const int rq = tid >> 6;
    const int hword = gm * 256 + w * 8 + gj;

    const unsigned arow = (unsigned)(mt * 16 + (lane & 15));
    const unsigned rb = arow * PROW;
    const unsigned asw = (arow & 7u) << 4;

    float cs = 0.f;
    long long budget = 500000;

    if (isL0) {
        // ================= LAYER-0 CREW =================
        int known = 0;   // throttle watermark: min h1 tag observed
        u32x4 xr[8];
#pragma unroll
        for (int i = 0; i < 8; ++i)
            xr[i] = ld16((const unsigned*)(x + (size_t)(i * 4 + rq) * (TT * DD) + cb * 4));
        VW(0);

        for (int c = 0; c < TT; ++c) {
            // stage x[c] -> in-region [0,512)
#pragma unroll
            for (int i = 0; i < 8; ++i) {
                unsigned row = (unsigned)(i * 4 + rq);
                uint2 pk;
                pk.x = f2bf(__uint_as_float(xr[i][0])) | (f2bf(__uint_as_float(xr[i][1])) << 16);
                pk.y = f2bf(__uint_as_float(xr[i][2])) | (f2bf(__uint_as_float(xr[i][3])) << 16);
                *(uint2*)(Ap + row * PROW + (((unsigned)(cb * 8)) ^ ((row & 7u) << 4))) = pk;
            }
            // issue h0[c] polls, then x[c+1] prefetch
            const unsigned* s0 = h0w + (size_t)(c & (RING0 - 1)) * HWORDS + tid * 4;
            u32x4 pv[8];
#pragma unroll
            for (int i = 0; i < 8; ++i) pv[i] = ld16_sys(s0 + i * 1024);
            if (c + 1 < TT) {
#pragma unroll
                for (int i = 0; i < 8; ++i)
                    xr[i] = ld16((const unsigned*)(x + (size_t)(i * 4 + rq) * (TT * DD)
                                                   + (size_t)(c + 1) * DD + cb * 4));
            }
            LBAR();   // B1: x staged

            // phase A: x-half MFMA hides the poll flight
            f32x4 acc = {0.f, 0.f, 0.f, 0.f};
#pragma unroll
            for (int kf = 0; kf < 8; ++kf) {
                unsigned kb = (unsigned)kf * 64u + ((unsigned)(lane >> 4)) * 16u;
                s16x8 a = *(const s16x8*)(Ap + rb + (kb ^ asw));
                acc = __builtin_amdgcn_mfma_f32_16x16x32_bf16(a, Bf[kf], acc, 0, 0, 0);
            }
            if (c + 1 < TT) VW(8); else VW(0);
            while (!tags_ok4(pv, (unsigned)c)) {
                if (--budget <= 0) break;
                __builtin_amdgcn_s_sleep(1);
#pragma unroll
                for (int i = 0; i < 8; ++i) pv[i] = ld16_sys(s0 + i * 1024);
                VW(0);
            }
            // unpack h0[c] -> h-region [512,1024)
#pragma unroll
            for (int i = 0; i < 8; ++i) {
                unsigned row = (unsigned)(i * 4 + rq);
                uint2 pk;
                pk.x = (pv[i][0] >> 16) | (pv[i][1] & 0xffff0000u);
                pk.y = (pv[i][2] >> 16) | (pv[i][3] & 0xffff0000u);
                *(uint2*)(Ap + row * PROW + ((512u + (unsigned)cb * 8u) ^ ((row & 7u) << 4))) = pk;
            }
            LBAR();   // B2: h staged

            // phase B: h-half MFMA
#pragma unroll
            for (int kf = 8; kf < 16; ++kf) {
                unsigned kb = (unsigned)kf * 64u + ((unsigned)(lane >> 4)) * 16u;
                s16x8 a = *(const s16x8*)(Ap + rb + (kb ^ asw));
                acc = __builtin_amdgcn_mfma_f32_16x16x32_bf16(a, Bf[kf], acc, 0, 0, 0);
            }
            {
                const int n = nt * 16 + (lane & 15);
                const int g = n >> 3, cl = n & 7;
#pragma unroll
                for (int r = 0; r < 4; ++r)
                    zbuf[g * 320 + (mt * 16 + (lane >> 4) * 4 + r) * 10 + cl] = acc[r];
            }
            VW(0);    // xr retired before next stage-x (loads ~1 cadence old: ~free)
            LBAR();   // B3: zbuf ready

            // gates
            float zi = zbuf[0 * 320 + gm * 10 + gj] + bi_;
            float zf = zbuf[1 * 320 + gm * 10 + gj] + bf_;
            float zg = zbuf[2 * 320 + gm * 10 + gj] + bg_;
            float zo = zbuf[3 * 320 + gm * 10 + gj] + bo_;
            cs = sigm(zf) * cs + sigm(zi) * tanh_f(zg);
            float h = sigm(zo) * tanh_f(cs);

            // throttle: before overwriting h0[c-63], need ALL L1 WGs past it.
            // Evidence: h1 slot (c-63)&3 row-0 tags all >= c-63. Watermark-cached.
            int T = c - 63;
            if (T > known) {
                const unsigned* trow = h1w + (size_t)(T & (RING1 - 1)) * HWORDS + lane * 4;
                for (;;) {
                    u32x4 tv = ld16_sys(trow);
                    VW(0);
                    int m = (int)(tv[0] & 0xffffu);
                    m = min(m, (int)(tv[1] & 0xffffu));
                    m = min(m, (int)(tv[2] & 0xffffu));
                    m = min(m, (int)(tv[3] & 0xffffu));
#pragma unroll
                    for (int off = 32; off; off >>= 1) m = min(m, __shfl_xor(m, off, 64));
                    if (m >= T) { known = m; break; }
                    if (--budget <= 0) break;
                    __builtin_amdgcn_s_sleep(4);
                }
            }
            st4_sys(h0w + (size_t)((c + 1) & (RING0 - 1)) * HWORDS + hword,
                    (f2bf(h) << 16) | (unsigned)(c + 1));
        }
    } else {
        // ================= LAYER-1 CREW =================
        u32x4 ph[8];   // prefetched h0[c+1] polls (issued at prev cadence end)
        {
            const unsigned* sp = h0w + (size_t)(1 & (RING0 - 1)) * HWORDS + tid * 4;
#pragma unroll
            for (int i = 0; i < 8; ++i) ph[i] = ld16_sys(sp + i * 1024);
        }
        for (int c = 0; c < TT; ++c) {
            const unsigned* s0 = h0w + (size_t)((c + 1) & (RING0 - 1)) * HWORDS + tid * 4;
            if (c == 0) VW(0); else VW(1);   // polls retired; newest publish store rides
            while (!tags_ok4(ph, (unsigned)(c + 1))) {
                if (--budget <= 0) break;
                __builtin_amdgcn_s_sleep(1);
#pragma unroll
                for (int i = 0; i < 8; ++i) ph[i] = ld16_sys(s0 + i * 1024);
                VW(0);
            }
            // unpack h0[c+1] (= y[c]) -> in-region [0,512)
#pragma unroll
            for (int i = 0; i < 8; ++i) {
                unsigned row = (unsigned)(i * 4 + rq);
                uint2 pk;
                pk.x = (ph[i][0] >> 16) | (ph[i][1] & 0xffff0000u);
                pk.y = (ph[i][2] >> 16) | (ph[i][3] & 0xffff0000u);
                *(uint2*)(Ap + row * PROW + (((unsigned)(cb * 8)) ^ ((row & 7u) << 4))) = pk;
            }
            // issue h1[c] polls NOW: flight overlaps phase A; check lands after
            // the producers' store-visibility window -> first check normally hits
            const unsigned* s1 = h1w + (size_t)(c & (RING1 - 1)) * HWORDS + tid * 4;
            u32x4 qv[8];
#pragma unroll
            for (int i = 0; i < 8; ++i) qv[i] = ld16_sys(s1 + i * 1024);
            LBAR();   // B1: in staged

            f32x4 acc = {0.f, 0.f, 0.f, 0.f};
#pragma unroll
            for (int kf = 0; kf < 8; ++kf) {
                unsigned kb = (unsigned)kf * 64u + ((unsigned)(lane >> 4)) * 16u;
                s16x8 a = *(const s16x8*)(Ap + rb + (kb ^ asw));
                acc = __builtin_amdgcn_mfma_f32_16x16x32_bf16(a, Bf[kf], acc, 0, 0, 0);
            }
            VW(0);
            while (!tags_ok4(qv, (unsigned)c)) {
                if (--budget <= 0) break;
                __builtin_amdgcn_s_sleep(1);
#pragma unroll
                for (int i = 0; i < 8; ++i) qv[i] = ld16_sys(s1 + i * 1024);
                VW(0);
            }
            // unpack h1[c] -> h-region [512,1024)
#pragma unroll
            for (int i = 0; i < 8; ++i) {
                unsigned row = (unsigned)(i * 4 + rq);
                uint2 pk;
                pk.x = (qv[i][0] >> 16) | (qv[i][1] & 0xffff0000u);
                pk.y = (qv[i][2] >> 16) | (qv[i][3] & 0xffff0000u);
                *(uint2*)(Ap + row * PROW + ((512u + (unsigned)cb * 8u) ^ ((row & 7u) << 4))) = pk;
            }
            LBAR();   // B2: h staged

#pragma unroll
            for (int kf = 8; kf < 16; ++kf) {
                unsigned kb = (unsigned)kf * 64u + ((unsigned)(lane >> 4)) * 16u;
                s16x8 a = *(const s16x8*)(Ap + rb + (kb ^ asw));
                acc = __builtin_amdgcn_mfma_f32_16x16x32_bf16(a, Bf[kf], acc, 0, 0, 0);
            }
            {
                const int n = nt * 16 + (lane & 15);
                const int g = n >> 3, cl = n & 7;
#pragma unroll
                for (int r = 0; r < 4; ++r)
                    zbuf[g * 320 + (mt * 16 + (lane >> 4) * 4 + r) * 10 + cl] = acc[r];
            }
            LBAR();   // B3: zbuf ready

            float zi = zbuf[0 * 320 + gm * 10 + gj] + bi_;
            float zf = zbuf[1 * 320 + gm * 10 + gj] + bf_;
            float zg = zbuf[2 * 320 + gm * 10 + gj] + bg_;
            float zo = zbuf[3 * 320 + gm * 10 + gj] + bo_;
            cs = sigm(zf) * cs + sigm(zi) * tanh_f(zg);
            float h = sigm(zo) * tanh_f(cs);

            // prefetch next cadence's h0[c+2] polls BEFORE the publish store
            // (so VW(1) next cadence leaves exactly the publish in flight)
            if (c + 1 < TT) {
                const unsigned* sn = h0w + (size_t)((c + 2) & (RING0 - 1)) * HWORDS + tid * 4;
#pragma unroll
                for (int i = 0; i < 8; ++i) ph[i] = ld16_sys(sn + i * 1024);
            }
            st4_sys(h1w + (size_t)((c + 1) & (RING1 - 1)) * HWORDS + hword,
                    (f2bf(h) << 16) | (unsigned)(c + 1));
        }
    }
}

// out = h1[T] @ Wd + bd  (32x256 @ 256x256, fp32); h1[T] = tagged words in ring slot TT%4 == 0.
__global__ void k_dense(const unsigned* __restrict__ h1last,
                        const float* __restrict__ Wd, const float* __restrict__ bd,
                        float* __restrict__ out)
{
    __shared__ float hs[256];
    const int m = blockIdx.x;
    const int o = threadIdx.x;
    hs[o] = bf2f(h1last[m * 256 + o] >> 16);
    __syncthreads();
    float acc = bd[o];
#pragma unroll 8
    for (int k = 0; k < 256; ++k)
        acc = fmaf(hs[k], Wd[k * 256 + o], acc);
    out[m * 256 + o] = acc;
}

extern "C" void kernel_launch(void* const* d_in, const int* in_sizes, int n_in,
                              void* d_out, int out_size, void* d_ws, size_t ws_size,
                              hipStream_t stream)
{
    const float* x   = (const float*)d_in[0];
    const float* Wi0 = (const float*)d_in[1];
    const float* Wh0 = (const float*)d_in[2];
    const float* b0  = (const float*)d_in[3];
    const float* Wi1 = (const float*)d_in[4];
    const float* Wh1 = (const float*)d_in[5];
    const float* b1  = (const float*)d_in[6];
    const float* Wd  = (const float*)d_in[7];
    const float* bd  = (const float*)d_in[8];
    float* out = (float*)d_out;

    char* ws = (char*)d_ws;
    unsigned* h0w = (unsigned*)ws;                                   // 64 slots = 2 MB
    unsigned* h1w = (unsigned*)(ws + (size_t)RING0 * HWORDS * 4);    // 4 slots = 128 KB

    k_init<<<dim3(RING0 * HWORDS / 256), dim3(256), 0, stream>>>(h0w, h1w);
    k_scan<<<dim3(64), dim3(256), 0, stream>>>(x, Wi0, Wh0, b0, Wi1, Wh1, b1, h0w, h1w);
    k_dense<<<dim3(32), dim3(256), 0, stream>>>(
        h1w + (size_t)(TT & (RING1 - 1)) * HWORDS, Wd, bd, out);
}

// Round 12
// 4633.635 us; speedup vs baseline: 2.3160x; 1.0658x over previous
//
#include <hip/hip_runtime.h>
#include <stdint.h>

#define TT 2048
#define DD 256
#define GG 1024
#define HWORDS 8192      // one slot: 32 WGs x (32 rows x 8 cols) tagged words, BLOCKED layout
#define RING0 64         // h0 ring slots (2MB)
#define RING1 4          // h1 ring slots
#define PROW 1024        // panel row stride bytes: [in(512) | h(512)]

typedef __attribute__((ext_vector_type(4))) float f32x4;
typedef __attribute__((ext_vector_type(8))) short s16x8;
typedef __attribute__((ext_vector_type(4))) unsigned u32x4;

static __device__ __forceinline__ unsigned f2bf(float f) {
    union { float f; unsigned u; } v; v.f = f;
    return (v.u + 0x7fffu + ((v.u >> 16) & 1u)) >> 16;
}
static __device__ __forceinline__ float bf2f(unsigned b) {
    union { unsigned u; float f; } v; v.u = b << 16;
    return v.f;
}
static __device__ __forceinline__ float sigm(float x) {
    return 1.0f / (1.0f + __expf(-x));
}
static __device__ __forceinline__ float tanh_f(float x) {
    x = fminf(15.0f, fmaxf(-15.0f, x));
    float e = __expf(2.0f * x);
    return (e - 1.0f) / (e + 1.0f);
}

static __device__ __forceinline__ u32x4 ld16_sys(const unsigned* p) {
    u32x4 r;
    asm volatile("global_load_dwordx4 %0, %1, off sc0 sc1"
                 : "=&v"(r) : "v"(p) : "memory");
    return r;
}
static __device__ __forceinline__ u32x4 ld16(const unsigned* p) {
    u32x4 r;
    asm volatile("global_load_dwordx4 %0, %1, off"
                 : "=&v"(r) : "v"(p) : "memory");
    return r;
}
static __device__ __forceinline__ void st4_sys(unsigned* p, unsigned d) {
    asm volatile("global_store_dword %0, %1, off sc0 sc1" :: "v"(p), "v"(d) : "memory");
}

#define VW(n) do { asm volatile("s_waitcnt vmcnt(" #n ")" ::: "memory"); \
                   __builtin_amdgcn_sched_barrier(0); } while (0)
#define LBAR() do { asm volatile("s_waitcnt lgkmcnt(0)\n\ts_barrier" ::: "memory"); \
                    __builtin_amdgcn_sched_barrier(0); } while (0)

// LIVENESS PIN for async asm loads: an inline-asm load's dest register must stay
// live until a waitcnt retires it, else the allocator reuses the physreg and the
// late writeback clobbers it (round-11 bug). Place AFTER the VW that retires them.
#define KEEP8(a) asm volatile("" :: "v"(a[0]), "v"(a[1]), "v"(a[2]), "v"(a[3]), \
                                    "v"(a[4]), "v"(a[5]), "v"(a[6]), "v"(a[7]))

static __device__ __forceinline__ bool tags_ok4(const u32x4 v[8], unsigned tag) {
    unsigned d = 0;
#pragma unroll
    for (int i = 0; i < 8; ++i)
        d |= (v[i][0] ^ tag) | (v[i][1] ^ tag) | (v[i][2] ^ tag) | (v[i][3] ^ tag);
    return (d & 0xffffu) == 0;
}

// Zero BOTH rings fully every launch (tag 0 == unpublished; replay-safe).
__global__ void k_init(unsigned* __restrict__ h0, unsigned* __restrict__ h1) {
    unsigned i = blockIdx.x * 256 + threadIdx.x;   // grid 2048 -> 524288 words
    h0[i] = 0u;
    if (i < RING1 * HWORDS) h1[i] = 0u;
}

// Two crews of 32 WGs (one kernel): blocks 0..31 = L0, 32..63 = L1.
// BLOCKED slot layout: word = w*256 + row*8 + col  ->  publish addr = base + w*256 + tid
// (one contiguous 1KB burst per WG). Ping-pong polls: batches A/B staggered; counted
// VW(8) retires exactly the older batch at each check. Loser batches stay pinned live
// (KEEP8) until the next cadence's VW(1) retires them.
__launch_bounds__(256, 1)
__global__ void k_scan(const float* __restrict__ x,
                       const float* __restrict__ Wi0, const float* __restrict__ Wh0,
                       const float* __restrict__ b0,
                       const float* __restrict__ Wi1, const float* __restrict__ Wh1,
                       const float* __restrict__ b1,
                       unsigned* h0w, unsigned* h1w)
{
    const int tid = threadIdx.x;
    const bool isL0 = (blockIdx.x < 32);
    const int w = blockIdx.x & 31;

    const float* Wi = isL0 ? Wi0 : Wi1;
    const float* Wh = isL0 ? Wh0 : Wh1;
    const float* bb = isL0 ? b0 : b1;

    __shared__ __align__(16) unsigned char Ap[32 * PROW];
    __shared__ float zbuf[4 * 32 * 10];

    const int lane = tid & 63;
    const int wid = tid >> 6;
    const int mt = wid & 1;
    const int nt = wid >> 1;

    // ---- weights as MFMA B-fragments ----
    s16x8 Bf[16];
    {
        const int jloc = lane & 15;
        const int lcol = nt * 16 + jloc;          // [i0-7 f0-7 | g0-7 o0-7]
        const int gate = lcol >> 3;
        const int jj = lcol & 7;
        const int gcol = gate * 256 + w * 8 + jj;
        const int krow = (lane >> 4) * 8;
#pragma unroll
        for (int kf = 0; kf < 16; ++kf) {
            s16x8 a;
#pragma unroll
            for (int j = 0; j < 8; ++j) {
                int k = kf * 32 + krow + j;
                float wv = (k < 256) ? Wi[(size_t)k * GG + gcol] : Wh[(size_t)(k - 256) * GG + gcol];
                a[j] = (short)f2bf(wv);
            }
            Bf[kf] = a;
        }
    }

    const int gm = tid >> 3;
    const int gj = tid & 7;
    const float bi_ = bb[0 * 256 + w * 8 + gj], bf_ = bb[1 * 256 + w * 8 + gj];
    const float bg_ = bb[2 * 256 + w * 8 + gj], bo_ = bb[3 * 256 + w * 8 + gj];

    const int cb = tid & 63;       // x staging roles
    const int rq = tid >> 6;

    // blocked-layout unpack decode (constant per thread)
    const unsigned urow = (unsigned)((tid >> 1) & 31);
    const unsigned usw = (urow & 7u) << 4;

    const unsigned arow = (unsigned)(mt * 16 + (lane & 15));
    const unsigned rb = arow * PROW;
    const unsigned asw = (arow & 7u) << 4;

    float cs = 0.f;
    long long budget = 500000;

#define UNP_STORE(A0, A1, A2, A3, BASE, I) do {                                   \
        uint2 pk_;                                                                \
        pk_.x = ((A0) >> 16) | ((A1) & 0xffff0000u);                              \
        pk_.y = ((A2) >> 16) | ((A3) & 0xffff0000u);                              \
        unsigned bcol_ = (unsigned)((I) * 4 + (tid >> 6)) * 16u                   \
                       + (unsigned)(tid & 1) * 8u;                                \
        *(uint2*)(Ap + urow * PROW + (((BASE) + bcol_) ^ usw)) = pk_;             \
    } while (0)

    if (isL0) {
        // ================= LAYER-0 CREW =================
        int known = 0;
        u32x4 xr[8];
#pragma unroll
        for (int i = 0; i < 8; ++i)
            xr[i] = ld16((const unsigned*)(x + (size_t)(i * 4 + rq) * (TT * DD) + cb * 4));
        VW(0);
        u32x4 pA[8] = {}, pB[8] = {};

        for (int c = 0; c < TT; ++c) {
            VW(1);   // retire residual poll batch + xpf; keep only newest publish store
            KEEP8(pA); KEEP8(pB);   // pin in-flight loser regs through retirement
            // stage x[c] -> in-region [0,512)
#pragma unroll
            for (int i = 0; i < 8; ++i) {
                unsigned row = (unsigned)(i * 4 + rq);
                uint2 pk;
                pk.x = f2bf(__uint_as_float(xr[i][0])) | (f2bf(__uint_as_float(xr[i][1])) << 16);
                pk.y = f2bf(__uint_as_float(xr[i][2])) | (f2bf(__uint_as_float(xr[i][3])) << 16);
                *(uint2*)(Ap + row * PROW + (((unsigned)(cb * 8)) ^ ((row & 7u) << 4))) = pk;
            }
            const unsigned* s0 = h0w + (size_t)(c & (RING0 - 1)) * HWORDS + tid * 4;
#pragma unroll
            for (int i = 0; i < 8; ++i) pA[i] = ld16_sys(s0 + i * 1024);
            LBAR();   // B1: x staged

            f32x4 acc = {0.f, 0.f, 0.f, 0.f};
#pragma unroll
            for (int kf = 0; kf < 8; ++kf) {
                unsigned kb = (unsigned)kf * 64u + ((unsigned)(lane >> 4)) * 16u;
                s16x8 a = *(const s16x8*)(Ap + rb + (kb ^ asw));
                acc = __builtin_amdgcn_mfma_f32_16x16x32_bf16(a, Bf[kf], acc, 0, 0, 0);
            }
#pragma unroll
            for (int i = 0; i < 8; ++i) pB[i] = ld16_sys(s0 + i * 1024);
            VW(8);    // in-flight store(<=1)+pA+pB -> retires store+pA
            bool wA = tags_ok4(pA, (unsigned)c);
            bool ok = wA;
            while (!ok) {
                if (--budget <= 0) break;
                __builtin_amdgcn_s_sleep(1);
#pragma unroll
                for (int i = 0; i < 8; ++i) pA[i] = ld16_sys(s0 + i * 1024);
                VW(8);            // retires pB
                if (tags_ok4(pB, (unsigned)c)) { ok = true; wA = false; break; }
                if (--budget <= 0) break;
                __builtin_amdgcn_s_sleep(1);
#pragma unroll
                for (int i = 0; i < 8; ++i) pB[i] = ld16_sys(s0 + i * 1024);
                VW(8);            // retires pA
                wA = tags_ok4(pA, (unsigned)c);
                ok = wA;
            }
            // select + unpack h0[c] -> h-region [512,1024)
#pragma unroll
            for (int i = 0; i < 8; ++i) {
                unsigned a0 = wA ? pA[i][0] : pB[i][0];
                unsigned a1 = wA ? pA[i][1] : pB[i][1];
                unsigned a2 = wA ? pA[i][2] : pB[i][2];
                unsigned a3 = wA ? pA[i][3] : pB[i][3];
                UNP_STORE(a0, a1, a2, a3, 512u, i);
            }
            // prefetch x[c+1] (retired at next VW(1))
            if (c + 1 < TT) {
#pragma unroll
                for (int i = 0; i < 8; ++i)
                    xr[i] = ld16((const unsigned*)(x + (size_t)(i * 4 + rq) * (TT * DD)
                                                   + (size_t)(c + 1) * DD + cb * 4));
            }
            LBAR();   // B2: h staged

#pragma unroll
            for (int kf = 8; kf < 16; ++kf) {
                unsigned kb = (unsigned)kf * 64u + ((unsigned)(lane >> 4)) * 16u;
                s16x8 a = *(const s16x8*)(Ap + rb + (kb ^ asw));
                acc = __builtin_amdgcn_mfma_f32_16x16x32_bf16(a, Bf[kf], acc, 0, 0, 0);
            }
            {
                const int n = nt * 16 + (lane & 15);
                const int g = n >> 3, cl = n & 7;
#pragma unroll
                for (int r = 0; r < 4; ++r)
                    zbuf[g * 320 + (mt * 16 + (lane >> 4) * 4 + r) * 10 + cl] = acc[r];
            }
            LBAR();   // B3: zbuf ready

            float zi = zbuf[0 * 320 + gm * 10 + gj] + bi_;
            float zf = zbuf[1 * 320 + gm * 10 + gj] + bf_;
            float zg = zbuf[2 * 320 + gm * 10 + gj] + bg_;
            float zo = zbuf[3 * 320 + gm * 10 + gj] + bo_;
            cs = sigm(zf) * cs + sigm(zi) * tanh_f(zg);
            float h = sigm(zo) * tanh_f(cs);

            // throttle (rare: ~1 poll round per 63 cadences): h1 tags >= c-63 proves
            // all L1 WGs consumed h0[c-63] whose slot we overwrite next.
            int T = c - 63;
            if (T > known) {
                const unsigned* trow = h1w + (size_t)(T & (RING1 - 1)) * HWORDS
                                     + (size_t)(lane & 31) * 256;
                for (;;) {
                    u32x4 tv = ld16_sys(trow);
                    VW(0);
                    int m = (int)(tv[0] & 0xffffu);
                    m = min(m, (int)(tv[1] & 0xffffu));
                    m = min(m, (int)(tv[2] & 0xffffu));
                    m = min(m, (int)(tv[3] & 0xffffu));
#pragma unroll
                    for (int off = 32; off; off >>= 1) m = min(m, __shfl_xor(m, off, 64));
                    if (m >= T) { known = m; break; }
                    if (--budget <= 0) break;
                    __builtin_amdgcn_s_sleep(4);
                }
            }
            st4_sys(h0w + (size_t)((c + 1) & (RING0 - 1)) * HWORDS + w * 256 + tid,
                    (f2bf(h) << 16) | (unsigned)(c + 1));
        }
    } else {
        // ================= LAYER-1 CREW =================
        u32x4 ph[8], qA[8] = {}, qB[8] = {};
        {
            const unsigned* sp = h0w + (size_t)1 * HWORDS + tid * 4;
#pragma unroll
            for (int i = 0; i < 8; ++i) ph[i] = ld16_sys(sp + i * 1024);
        }
        for (int c = 0; c < TT; ++c) {
            if (c == 0) { VW(0); } else { VW(1); }   // retire residual q + ph; keep store
            KEEP8(qA); KEEP8(qB);   // pin in-flight loser regs through retirement
            const unsigned* s0 = h0w + (size_t)((c + 1) & (RING0 - 1)) * HWORDS + tid * 4;
            while (!tags_ok4(ph, (unsigned)(c + 1))) {   // feed-forward: normally hits
                if (--budget <= 0) break;
                __builtin_amdgcn_s_sleep(1);
#pragma unroll
                for (int i = 0; i < 8; ++i) ph[i] = ld16_sys(s0 + i * 1024);
                VW(0);
            }
            // unpack h0[c+1] -> in-region [0,512)
#pragma unroll
            for (int i = 0; i < 8; ++i)
                UNP_STORE(ph[i][0], ph[i][1], ph[i][2], ph[i][3], 0u, i);

            const unsigned* s1 = h1w + (size_t)(c & (RING1 - 1)) * HWORDS + tid * 4;
#pragma unroll
            for (int i = 0; i < 8; ++i) qA[i] = ld16_sys(s1 + i * 1024);
            LBAR();   // B1: in staged

            f32x4 acc = {0.f, 0.f, 0.f, 0.f};
#pragma unroll
            for (int kf = 0; kf < 8; ++kf) {
                unsigned kb = (unsigned)kf * 64u + ((unsigned)(lane >> 4)) * 16u;
                s16x8 a = *(const s16x8*)(Ap + rb + (kb ^ asw));
                acc = __builtin_amdgcn_mfma_f32_16x16x32_bf16(a, Bf[kf], acc, 0, 0, 0);
            }
#pragma unroll
            for (int i = 0; i < 8; ++i) qB[i] = ld16_sys(s1 + i * 1024);
            VW(8);    // retires store+qA
            bool wA = tags_ok4(qA, (unsigned)c);
            bool ok = wA;
            while (!ok) {
                if (--budget <= 0) break;
                __builtin_amdgcn_s_sleep(1);
#pragma unroll
                for (int i = 0; i < 8; ++i) qA[i] = ld16_sys(s1 + i * 1024);
                VW(8);            // retires qB
                if (tags_ok4(qB, (unsigned)c)) { ok = true; wA = false; break; }
                if (--budget <= 0) break;
                __builtin_amdgcn_s_sleep(1);
#pragma unroll
                for (int i = 0; i < 8; ++i) qB[i] = ld16_sys(s1 + i * 1024);
                VW(8);            // retires qA
                wA = tags_ok4(qA, (unsigned)c);
                ok = wA;
            }
            // select + unpack h1[c] -> h-region [512,1024)
#pragma unroll
            for (int i = 0; i < 8; ++i) {
                unsigned a0 = wA ? qA[i][0] : qB[i][0];
                unsigned a1 = wA ? qA[i][1] : qB[i][1];
                unsigned a2 = wA ? qA[i][2] : qB[i][2];
                unsigned a3 = wA ? qA[i][3] : qB[i][3];
                UNP_STORE(a0, a1, a2, a3, 512u, i);
            }
            LBAR();   // B2: h staged

#pragma unroll
            for (int kf = 8; kf < 16; ++kf) {
                unsigned kb = (unsigned)kf * 64u + ((unsigned)(lane >> 4)) * 16u;
                s16x8 a = *(const s16x8*)(Ap + rb + (kb ^ asw));
                acc = __builtin_amdgcn_mfma_f32_16x16x32_bf16(a, Bf[kf], acc, 0, 0, 0);
            }
            {
                const int n = nt * 16 + (lane & 15);
                const int g = n >> 3, cl = n & 7;
#pragma unroll
                for (int r = 0; r < 4; ++r)
                    zbuf[g * 320 + (mt * 16 + (lane >> 4) * 4 + r) * 10 + cl] = acc[r];
            }
            LBAR();   // B3: zbuf ready

            float zi = zbuf[0 * 320 + gm * 10 + gj] + bi_;
            float zf = zbuf[1 * 320 + gm * 10 + gj] + bf_;
            float zg = zbuf[2 * 320 + gm * 10 + gj] + bg_;
            float zo = zbuf[3 * 320 + gm * 10 + gj] + bo_;
            cs = sigm(zf) * cs + sigm(zi) * tanh_f(zg);
            float h = sigm(zo) * tanh_f(cs);

            // prefetch next h0 polls BEFORE publish (next VW(1) keeps only the store)
            if (c + 1 < TT) {
                const unsigned* sn = h0w + (size_t)((c + 2) & (RING0 - 1)) * HWORDS + tid * 4;
#pragma unroll
                for (int i = 0; i < 8; ++i) ph[i] = ld16_sys(sn + i * 1024);
            }
            st4_sys(h1w + (size_t)((c + 1) & (RING1 - 1)) * HWORDS + w * 256 + tid,
                    (f2bf(h) << 16) | (unsigned)(c + 1));
        }
    }
#undef UNP_STORE
}

// out = h1[T] @ Wd + bd; h1 ring slot TT%4 == 0 holds blocked tagged words.
__global__ void k_dense(const unsigned* __restrict__ h1last,
                        const float* __restrict__ Wd, const float* __restrict__ bd,
                        float* __restrict__ out)
{
    __shared__ float hs[256];
    const int m = blockIdx.x;
    const int o = threadIdx.x;
    hs[o] = bf2f(h1last[(o >> 3) * 256 + m * 8 + (o & 7)] >> 16);
    __syncthreads();
    float acc = bd[o];
#pragma unroll 8
    for (int k = 0; k < 256; ++k)
        acc = fmaf(hs[k], Wd[k * 256 + o], acc);
    out[m * 256 + o] = acc;
}

extern "C" void kernel_launch(void* const* d_in, const int* in_sizes, int n_in,
                              void* d_out, int out_size, void* d_ws, size_t ws_size,
                              hipStream_t stream)
{
    const float* x   = (const float*)d_in[0];
    const float* Wi0 = (const float*)d_in[1];
    const float* Wh0 = (const float*)d_in[2];
    const float* b0  = (const float*)d_in[3];
    const float* Wi1 = (const float*)d_in[4];
    const float* Wh1 = (const float*)d_in[5];
    const float* b1  = (const float*)d_in[6];
    const float* Wd  = (const float*)d_in[7];
    const float* bd  = (const float*)d_in[8];
    float* out = (float*)d_out;

    char* ws = (char*)d_ws;
    unsigned* h0w = (unsigned*)ws;                                   // 64 slots = 2 MB
    unsigned* h1w = (unsigned*)(ws + (size_t)RING0 * HWORDS * 4);    // 4 slots = 128 KB

    k_init<<<dim3(RING0 * HWORDS / 256), dim3(256), 0, stream>>>(h0w, h1w);
    k_scan<<<dim3(64), dim3(256), 0, stream>>>(x, Wi0, Wh0, b0, Wi1, Wh1, b1, h0w, h1w);
    k_dense<<<dim3(32), dim3(256), 0, stream>>>(
        h1w + (size_t)(TT & (RING1 - 1)) * HWORDS, Wd, bd, out);
}